// Round 2
// baseline (4020.361 us; speedup 1.0000x reference)
//
#include <hip/hip_runtime.h>

typedef unsigned short bf16_t;

// ---------------- conversions ----------------
__device__ __forceinline__ float bf2f(bf16_t u) {
  union { unsigned int i; float f; } v; v.i = ((unsigned int)u) << 16; return v.f;
}
__device__ __forceinline__ bf16_t f2bf(float f) {
  union { float f; unsigned int i; } v; v.f = f;
  unsigned int u = v.i;
  u += 0x7fffu + ((u >> 16) & 1u);   // RNE
  return (bf16_t)(u >> 16);
}
__device__ __forceinline__ float gelu_exact(float x) {
  return 0.5f * x * (1.0f + erff(x * 0.7071067811865475f));
}

// ---------------- LayerNorm: one wave per row of 512 ----------------
__global__ __launch_bounds__(256) void ln_kernel(const float* __restrict__ x,
                                                 const float* __restrict__ g,
                                                 const float* __restrict__ bta,
                                                 float* __restrict__ y) {
  const int w = threadIdx.x >> 6, lane = threadIdx.x & 63;
  const long row = (long)blockIdx.x * 4 + w;
  const long base = row * 512;
  const int c0 = lane << 2;
  float v[8];
  float4 f0 = *(const float4*)(x + base + c0);
  float4 f1 = *(const float4*)(x + base + 256 + c0);
  v[0]=f0.x; v[1]=f0.y; v[2]=f0.z; v[3]=f0.w;
  v[4]=f1.x; v[5]=f1.y; v[6]=f1.z; v[7]=f1.w;
  float s = 0.f;
#pragma unroll
  for (int c=0;c<8;++c) s += v[c];
#pragma unroll
  for (int o=32;o>0;o>>=1) s += __shfl_xor(s, o);
  const float mean = s * 0.001953125f;
  float ss = 0.f;
#pragma unroll
  for (int c=0;c<8;++c) { float d = v[c]-mean; ss += d*d; }
#pragma unroll
  for (int o=32;o>0;o>>=1) ss += __shfl_xor(ss, o);
  const float rstd = rsqrtf(ss * 0.001953125f + 1e-5f);
#pragma unroll
  for (int c=0;c<4;++c)
    y[base + c0 + c] = (v[c]-mean)*rstd*g[c0+c] + bta[c0+c];
#pragma unroll
  for (int c=0;c<4;++c)
    y[base + 256 + c0 + c] = (v[4+c]-mean)*rstd*g[256+c0+c] + bta[256+c0+c];
}

// ---------------- GEMM  C = A @ W^T  (+bias, gelu, scale, +res) ----------------
// batched over blockIdx.z with per-operand element strides; per-operand bf16 flags
// (all inputs are fp32 in this problem; flags kept for flexibility).
struct GemmNT {
  const void* A; const void* W; const void* bias; const void* res; void* C;
  long lda, sAz;
  long ldw, sWz;
  long ldr, sRz;
  long ldc, sCz;
  int K;
  int aBf, wBf, rBf, cBf, act;
  float scale;
};

__global__ __launch_bounds__(256) void gemm_nt_kernel(GemmNT p) {
  __shared__ float As[16][68];   // [k][m], pad 68 keeps float4 reads aligned
  __shared__ float Ws[16][68];   // [k][n]
  const int tid = threadIdx.x;
  const int tx = tid & 15, ty = tid >> 4;
  const long z = blockIdx.z;
  const long m0 = (long)blockIdx.y << 6;
  const long n0 = (long)blockIdx.x << 6;
  const int lr = tid >> 2;          // 0..63 row within tile
  const int lk = (tid & 3) << 2;    // 0,4,8,12 k offset
  const long aBase = z * p.sAz + (m0 + lr) * p.lda + lk;
  const long wBase = z * p.sWz + (n0 + lr) * p.ldw + lk;
  float acc[4][4];
#pragma unroll
  for (int i=0;i<4;++i)
#pragma unroll
    for (int j=0;j<4;++j) acc[i][j]=0.f;

  for (int kc = 0; kc < p.K; kc += 16) {
    float4 a4, w4;
    if (p.aBf) { ushort4 u = *(const ushort4*)((const bf16_t*)p.A + aBase + kc);
                 a4 = make_float4(bf2f(u.x), bf2f(u.y), bf2f(u.z), bf2f(u.w)); }
    else       { a4 = *(const float4*)((const float*)p.A + aBase + kc); }
    if (p.wBf) { ushort4 u = *(const ushort4*)((const bf16_t*)p.W + wBase + kc);
                 w4 = make_float4(bf2f(u.x), bf2f(u.y), bf2f(u.z), bf2f(u.w)); }
    else       { w4 = *(const float4*)((const float*)p.W + wBase + kc); }
    __syncthreads();
    As[lk+0][lr]=a4.x; As[lk+1][lr]=a4.y; As[lk+2][lr]=a4.z; As[lk+3][lr]=a4.w;
    Ws[lk+0][lr]=w4.x; Ws[lk+1][lr]=w4.y; Ws[lk+2][lr]=w4.z; Ws[lk+3][lr]=w4.w;
    __syncthreads();
#pragma unroll
    for (int kk = 0; kk < 16; ++kk) {
      const float4 av = *(const float4*)&As[kk][ty<<2];
      const float4 wv = *(const float4*)&Ws[kk][tx<<2];
      float a_[4] = {av.x, av.y, av.z, av.w};
      float w_[4] = {wv.x, wv.y, wv.z, wv.w};
#pragma unroll
      for (int i=0;i<4;++i)
#pragma unroll
        for (int j=0;j<4;++j) acc[i][j] += a_[i]*w_[j];
    }
  }

  float bv[4] = {0.f,0.f,0.f,0.f};
  if (p.bias) {
    const float* bb = (const float*)p.bias;
#pragma unroll
    for (int j=0;j<4;++j) bv[j] = bb[n0 + (tx<<2) + j];
  }
  const long cz = z * p.sCz, rz = z * p.sRz;
#pragma unroll
  for (int i=0;i<4;++i) {
    const long row = m0 + (ty<<2) + i;
    float o[4];
#pragma unroll
    for (int j=0;j<4;++j) {
      float t = acc[i][j] + bv[j];
      if (p.act) t = gelu_exact(t);
      t *= p.scale;
      if (p.res) {
        const long ri = rz + row * p.ldr + n0 + (tx<<2) + j;
        t += p.rBf ? bf2f(((const bf16_t*)p.res)[ri]) : ((const float*)p.res)[ri];
      }
      o[j] = t;
    }
    const long ci = cz + row * p.ldc + n0 + (tx<<2);
    if (p.cBf) {
      bf16_t* cp = (bf16_t*)p.C + ci;
#pragma unroll
      for (int j=0;j<4;++j) cp[j] = f2bf(o[j]);
    } else {
      *(float4*)((float*)p.C + ci) = make_float4(o[0],o[1],o[2],o[3]);
    }
  }
}

// ---------------- GEMM  C = A @ B  (fp32 only, attention @ V) ----------------
struct GemmNN {
  const float* A; const float* B; float* C;
  long lda, sAz, ldb, sBz, ldc, sCz;
  int K;
};

__global__ __launch_bounds__(256) void gemm_nn_kernel(GemmNN p) {
  __shared__ float As[16][68];
  __shared__ float Bs[16][68];
  const int tid = threadIdx.x;
  const int tx = tid & 15, ty = tid >> 4;
  const long z = blockIdx.z;
  const long m0 = (long)blockIdx.y << 6;
  const long n0 = (long)blockIdx.x << 6;
  const int lrA = tid >> 2, lkA = (tid & 3) << 2;
  const int krB = tid >> 4, lnB = (tid & 15) << 2;
  const long aBase = z * p.sAz + (m0 + lrA) * p.lda + lkA;
  const long bBase = z * p.sBz + n0 + lnB;
  float acc[4][4];
#pragma unroll
  for (int i=0;i<4;++i)
#pragma unroll
    for (int j=0;j<4;++j) acc[i][j]=0.f;

  for (int kc = 0; kc < p.K; kc += 16) {
    float4 a4 = *(const float4*)(p.A + aBase + kc);
    float4 b4 = *(const float4*)(p.B + bBase + (long)(kc + krB) * p.ldb);
    __syncthreads();
    As[lkA+0][lrA]=a4.x; As[lkA+1][lrA]=a4.y; As[lkA+2][lrA]=a4.z; As[lkA+3][lrA]=a4.w;
    *(float4*)&Bs[krB][lnB] = b4;
    __syncthreads();
#pragma unroll
    for (int kk = 0; kk < 16; ++kk) {
      const float4 av = *(const float4*)&As[kk][ty<<2];
      const float4 wv = *(const float4*)&Bs[kk][tx<<2];
      float a_[4] = {av.x, av.y, av.z, av.w};
      float w_[4] = {wv.x, wv.y, wv.z, wv.w};
#pragma unroll
      for (int i=0;i<4;++i)
#pragma unroll
        for (int j=0;j<4;++j) acc[i][j] += a_[i]*w_[j];
    }
  }
  const long cz = z * p.sCz;
#pragma unroll
  for (int i=0;i<4;++i) {
    const long row = m0 + (ty<<2) + i;
    *(float4*)(p.C + cz + row * p.ldc + n0 + (tx<<2)) =
        make_float4(acc[i][0], acc[i][1], acc[i][2], acc[i][3]);
  }
}

// ---------------- softmax over a row (block per row) ----------------
template <int PER>
__global__ __launch_bounds__(256) void softmax_kernel(float* __restrict__ s) {
  float* p = s + (long)blockIdx.x * (PER * 256);
  const int tid = threadIdx.x;
  float v[PER];
  float vmax = -3.4028235e38f;
#pragma unroll
  for (int c=0;c<PER;++c) { v[c] = p[tid + (c<<8)]; vmax = fmaxf(vmax, v[c]); }
#pragma unroll
  for (int o=32;o>0;o>>=1) vmax = fmaxf(vmax, __shfl_xor(vmax, o));
  __shared__ float redm[4], reds[4];
  if ((tid & 63) == 0) redm[tid >> 6] = vmax;
  __syncthreads();
  vmax = fmaxf(fmaxf(redm[0], redm[1]), fmaxf(redm[2], redm[3]));
  float sum = 0.f;
#pragma unroll
  for (int c=0;c<PER;++c) { v[c] = __expf(v[c] - vmax); sum += v[c]; }
#pragma unroll
  for (int o=32;o>0;o>>=1) sum += __shfl_xor(sum, o);
  if ((tid & 63) == 0) reds[tid >> 6] = sum;
  __syncthreads();
  sum = reds[0] + reds[1] + reds[2] + reds[3];
  const float inv = 1.0f / sum;
#pragma unroll
  for (int c=0;c<PER;++c) p[tid + (c<<8)] = v[c] * inv;
}

// ---------------- concat [4096][512]+[4096][512] -> [4096][1024] ----------------
__global__ __launch_bounds__(256) void concat_kernel(const float4* __restrict__ a,
                                                     const float4* __restrict__ b,
                                                     float4* __restrict__ o) {
  const long idx = (long)blockIdx.x * 256 + threadIdx.x;  // over 4096*256 float4
  const long r = idx >> 8, c = idx & 255;
  o[idx] = (c < 128) ? a[r*128 + c] : b[r*128 + (c - 128)];
}

// ---------------- host ----------------
// ws layout (fp32 elements); total 58,720,256 floats = 224 MiB
#define OFF_H    0L
#define OFF_QKV  2097152L
#define OFF_O    8388608L     // o -> ff1g -> sm
#define OFF_X    10485760L
#define OFF_MSCA 12582912L
#define OFF_SMF  14680064L
#define OFF_KV   16777216L    // kv [32768,1024]; later cat + fc1g
#define OFF_CAT  16777216L
#define OFF_FC1  20971520L
#define OFF_SC   50331648L    // scores scratch (max 8.39M floats)

static GemmNT nt0() {
  GemmNT p{};
  p.scale = 1.0f;
  return p;
}

extern "C" void kernel_launch(void* const* d_in, const int* in_sizes, int n_in,
                              void* d_out, int out_size, void* d_ws, size_t ws_size,
                              hipStream_t stream) {
  const float* motion      = (const float*)d_in[0];
  const float* scene_feats = (const float*)d_in[2];
  const float* prior       = (const float*)d_in[3];
  const float* ln1_g = (const float*)d_in[4];
  const float* ln1_b = (const float*)d_in[5];
  const float* qkv_w = (const float*)d_in[6];
  const float* qkv_b = (const float*)d_in[7];
  const float* out_w = (const float*)d_in[8];
  const float* out_b = (const float*)d_in[9];
  const float* ln2_g = (const float*)d_in[10];
  const float* ln2_b = (const float*)d_in[11];
  const float* ff1_w = (const float*)d_in[12];
  const float* ff1_b = (const float*)d_in[13];
  const float* ff2_w = (const float*)d_in[14];
  const float* ff2_b = (const float*)d_in[15];
  const float* saq_w = (const float*)d_in[16];
  const float* saq_b = (const float*)d_in[17];
  const float* sakv_w = (const float*)d_in[18];
  const float* sakv_b = (const float*)d_in[19];
  const float* saout_w = (const float*)d_in[20];
  const float* saout_b = (const float*)d_in[21];
  const float* fc1_w = (const float*)d_in[22];
  const float* fc1_b = (const float*)d_in[23];
  const float* fc2_w = (const float*)d_in[24];
  const float* fc2_b = (const float*)d_in[25];
  float* ws = (float*)d_ws;
  const dim3 B256(256);

  // 1. h = LN1(motion)
  ln_kernel<<<1024, B256, 0, stream>>>(motion, ln1_g, ln1_b, ws + OFF_H);

  // 2. qkv = h @ qkv_w^T + b    [4096,1536]
  { GemmNT p = nt0();
    p.A = ws + OFF_H; p.lda = 512;
    p.W = qkv_w; p.ldw = 512;
    p.bias = qkv_b;
    p.C = ws + OFF_QKV; p.ldc = 1536;
    p.K = 512;
    gemm_nt_kernel<<<dim3(1536/64, 4096/64, 1), B256, 0, stream>>>(p); }

  // 3. encoder attention, per batch (z = 8 heads)
  for (int b = 0; b < 8; ++b) {
    const float* qkvb = ws + OFF_QKV + (long)b * 786432;
    { GemmNT p = nt0();                 // scores = q @ k^T * 0.125
      p.A = qkvb; p.lda = 1536; p.sAz = 64;
      p.W = qkvb + 512; p.ldw = 1536; p.sWz = 64;
      p.C = ws + OFF_SC; p.ldc = 512; p.sCz = 262144;
      p.K = 64; p.scale = 0.125f;
      gemm_nt_kernel<<<dim3(8, 8, 8), B256, 0, stream>>>(p); }
    softmax_kernel<2><<<4096, B256, 0, stream>>>(ws + OFF_SC);
    { GemmNN p{};                       // o = P @ v
      p.A = ws + OFF_SC; p.lda = 512; p.sAz = 262144;
      p.B = qkvb + 1024; p.ldb = 1536; p.sBz = 64;
      p.C = ws + OFF_O + (long)b * 262144; p.ldc = 512; p.sCz = 64;
      p.K = 512;
      gemm_nn_kernel<<<dim3(1, 8, 8), B256, 0, stream>>>(p); }
  }

  // 4. x = motion + o @ out_w^T + b
  { GemmNT p = nt0();
    p.A = ws + OFF_O; p.lda = 512;
    p.W = out_w; p.ldw = 512;
    p.bias = out_b;
    p.res = motion; p.ldr = 512;
    p.C = ws + OFF_X; p.ldc = 512;
    p.K = 512;
    gemm_nt_kernel<<<dim3(8, 64, 1), B256, 0, stream>>>(p); }

  // 5. h = LN2(x)
  ln_kernel<<<1024, B256, 0, stream>>>(ws + OFF_X, ln2_g, ln2_b, ws + OFF_H);

  // 6. ff1g = gelu(h @ ff1_w^T + b)
  { GemmNT p = nt0();
    p.A = ws + OFF_H; p.lda = 512;
    p.W = ff1_w; p.ldw = 512;
    p.bias = ff1_b; p.act = 1;
    p.C = ws + OFF_O; p.ldc = 512;
    p.K = 512;
    gemm_nt_kernel<<<dim3(8, 64, 1), B256, 0, stream>>>(p); }

  // 7. msca = x + ff1g @ ff2_w^T + b
  { GemmNT p = nt0();
    p.A = ws + OFF_O; p.lda = 512;
    p.W = ff2_w; p.ldw = 512;
    p.bias = ff2_b;
    p.res = ws + OFF_X; p.ldr = 512;
    p.C = ws + OFF_MSCA; p.ldc = 512;
    p.K = 512;
    gemm_nt_kernel<<<dim3(8, 64, 1), B256, 0, stream>>>(p); }

  // 8. q_sa = (msca @ saq_w^T + b) * 512^-0.5   -> OFF_H (reused)
  { GemmNT p = nt0();
    p.A = ws + OFF_MSCA; p.lda = 512;
    p.W = saq_w; p.ldw = 512;
    p.bias = saq_b; p.scale = 0.04419417382415922f;
    p.C = ws + OFF_H; p.ldc = 512;
    p.K = 512;
    gemm_nt_kernel<<<dim3(8, 64, 1), B256, 0, stream>>>(p); }

  // 9. kv = scene_feats @ sakv_w^T + b   [32768,1024]
  { GemmNT p = nt0();
    p.A = scene_feats; p.lda = 512;
    p.W = sakv_w; p.ldw = 512;
    p.bias = sakv_b;
    p.C = ws + OFF_KV; p.ldc = 1024;
    p.K = 512;
    gemm_nt_kernel<<<dim3(16, 512, 1), B256, 0, stream>>>(p); }

  // 10. semantic-aware attention, per batch (z = 4 heads).
  // faithful torch reshape: q head h = contiguous [512,128] block at offset h*65536.
  for (int b = 0; b < 8; ++b) {
    { GemmNT p = nt0();                 // scores = q @ k^T + prior
      p.A = ws + OFF_H + (long)b * 262144; p.lda = 128; p.sAz = 65536;
      p.W = ws + OFF_KV + (long)b * 4194304; p.ldw = 1024; p.sWz = 128;
      p.res = prior + (long)b * 2097152; p.ldr = 4096; p.sRz = 0;
      p.C = ws + OFF_SC; p.ldc = 4096; p.sCz = 2097152;
      p.K = 128;
      gemm_nt_kernel<<<dim3(64, 8, 4), B256, 0, stream>>>(p); }
    softmax_kernel<16><<<2048, B256, 0, stream>>>(ws + OFF_SC);
    { GemmNN p{};                       // sm = P @ v
      p.A = ws + OFF_SC; p.lda = 4096; p.sAz = 2097152;
      p.B = ws + OFF_KV + (long)b * 4194304 + 512; p.ldb = 1024; p.sBz = 128;
      p.C = ws + OFF_O + (long)b * 262144; p.ldc = 512; p.sCz = 128;
      p.K = 4096;
      gemm_nn_kernel<<<dim3(2, 8, 4), B256, 0, stream>>>(p); }
  }

  // 11. smf = sm @ saout_w^T + b
  { GemmNT p = nt0();
    p.A = ws + OFF_O; p.lda = 512;
    p.W = saout_w; p.ldw = 512;
    p.bias = saout_b;
    p.C = ws + OFF_SMF; p.ldc = 512;
    p.K = 512;
    gemm_nt_kernel<<<dim3(8, 64, 1), B256, 0, stream>>>(p); }

  // 12. cat = [msca, smf]
  concat_kernel<<<4096, B256, 0, stream>>>((const float4*)(ws + OFF_MSCA),
                                           (const float4*)(ws + OFF_SMF),
                                           (float4*)(ws + OFF_CAT));

  // 13. fc1g = gelu(cat @ fc1_w^T + b)   [4096,2048]
  { GemmNT p = nt0();
    p.A = ws + OFF_CAT; p.lda = 1024;
    p.W = fc1_w; p.ldw = 1024;
    p.bias = fc1_b; p.act = 1;
    p.C = ws + OFF_FC1; p.ldc = 2048;
    p.K = 1024;
    gemm_nt_kernel<<<dim3(32, 64, 1), B256, 0, stream>>>(p); }

  // 14. out = fc1g @ fc2_w^T + b  -> d_out (fp32)
  { GemmNT p = nt0();
    p.A = ws + OFF_FC1; p.lda = 2048;
    p.W = fc2_w; p.ldw = 2048;
    p.bias = fc2_b;
    p.C = d_out; p.ldc = 512;
    p.K = 2048;
    gemm_nt_kernel<<<dim3(8, 64, 1), B256, 0, stream>>>(p); }
}

// Round 3
// 1417.592 us; speedup vs baseline: 2.8361x; 2.8361x over previous
//
#include <hip/hip_runtime.h>

typedef unsigned short bf16_t;
typedef __attribute__((ext_vector_type(8))) short bf16x8;
typedef __attribute__((ext_vector_type(4))) float f32x4;

// ---------------- conversions ----------------
__device__ __forceinline__ float bf2f(bf16_t u) {
  union { unsigned int i; float f; } v; v.i = ((unsigned int)u) << 16; return v.f;
}
__device__ __forceinline__ bf16_t f2bf(float f) {
  union { float f; unsigned int i; } v; v.f = f;
  unsigned int u = v.i;
  u += 0x7fffu + ((u >> 16) & 1u);   // RNE
  return (bf16_t)(u >> 16);
}
__device__ __forceinline__ float gelu_exact(float x) {
  return 0.5f * x * (1.0f + erff(x * 0.7071067811865475f));
}

// ---------------- fp32 -> bf16 convert ----------------
__global__ __launch_bounds__(256) void f2bf_kernel(const float4* __restrict__ s,
                                                   ushort4* __restrict__ d, int n4) {
  int i = blockIdx.x * 256 + threadIdx.x;
  if (i < n4) {
    float4 f = s[i];
    ushort4 u; u.x = f2bf(f.x); u.y = f2bf(f.y); u.z = f2bf(f.z); u.w = f2bf(f.w);
    d[i] = u;
  }
}

// ---------------- LayerNorm: one wave per row of 512, fp32 in -> bf16 out ----------------
__global__ __launch_bounds__(256) void ln_kernel(const float* __restrict__ x,
                                                 const float* __restrict__ g,
                                                 const float* __restrict__ bta,
                                                 bf16_t* __restrict__ y) {
  const int w = threadIdx.x >> 6, lane = threadIdx.x & 63;
  const long row = (long)blockIdx.x * 4 + w;
  const long base = row * 512;
  const int c0 = lane << 2;
  float v[8];
  float4 f0 = *(const float4*)(x + base + c0);
  float4 f1 = *(const float4*)(x + base + 256 + c0);
  v[0]=f0.x; v[1]=f0.y; v[2]=f0.z; v[3]=f0.w;
  v[4]=f1.x; v[5]=f1.y; v[6]=f1.z; v[7]=f1.w;
  float s = 0.f;
#pragma unroll
  for (int c=0;c<8;++c) s += v[c];
#pragma unroll
  for (int o=32;o>0;o>>=1) s += __shfl_xor(s, o);
  const float mean = s * 0.001953125f;
  float ss = 0.f;
#pragma unroll
  for (int c=0;c<8;++c) { float d = v[c]-mean; ss += d*d; }
#pragma unroll
  for (int o=32;o>0;o>>=1) ss += __shfl_xor(ss, o);
  const float rstd = rsqrtf(ss * 0.001953125f + 1e-5f);
  ushort4 o0, o1;
  o0.x = f2bf((v[0]-mean)*rstd*g[c0+0] + bta[c0+0]);
  o0.y = f2bf((v[1]-mean)*rstd*g[c0+1] + bta[c0+1]);
  o0.z = f2bf((v[2]-mean)*rstd*g[c0+2] + bta[c0+2]);
  o0.w = f2bf((v[3]-mean)*rstd*g[c0+3] + bta[c0+3]);
  o1.x = f2bf((v[4]-mean)*rstd*g[256+c0+0] + bta[256+c0+0]);
  o1.y = f2bf((v[5]-mean)*rstd*g[256+c0+1] + bta[256+c0+1]);
  o1.z = f2bf((v[6]-mean)*rstd*g[256+c0+2] + bta[256+c0+2]);
  o1.w = f2bf((v[7]-mean)*rstd*g[256+c0+3] + bta[256+c0+3]);
  *(ushort4*)(y + base + c0) = o0;
  *(ushort4*)(y + base + 256 + c0) = o1;
}

// ---------------- MFMA GEMM  C = A @ W^T  (bf16 in, +bias/gelu/scale/+res fp32) ------------
// z decomposed: zb = z / zdiv, zh = z % zdiv; per-operand (b,h) strides.
struct MmaNT {
  const bf16_t* A; const bf16_t* W; const float* bias; const float* res; void* C;
  long lda, sAb, sAh;
  long ldw, sWb, sWh;
  long ldr, sRb, sRh;
  long ldc, sCb, sCh;
  int K, zdiv, cBf, act;
  float scale;
};

template <int MT>
__global__ __launch_bounds__(256) void mma_nt_kernel(MmaNT p) {
  constexpr int FM = MT / 32;          // m-frags per wave (wave covers MT/2 rows)
  __shared__ bf16_t Al[MT * 40];       // rows padded to 40 bf16 (80B: 16B-aligned, 2-way banks)
  __shared__ bf16_t Wl[128 * 40];
  const int tid = threadIdx.x;
  const int wid = tid >> 6, lane = tid & 63;
  const int wm = wid & 1, wn = wid >> 1;     // waves 2x2 over (M/2, 128/2)
  const int quad = lane >> 4, l16 = lane & 15;
  const int z = blockIdx.z;
  const int zb = z / p.zdiv, zh = z % p.zdiv;
  const long m0 = (long)blockIdx.y * MT;
  const long n0 = (long)blockIdx.x * 128;
  const bf16_t* Ag = p.A + (long)zb * p.sAb + (long)zh * p.sAh + m0 * p.lda;
  const bf16_t* Wg = p.W + (long)zb * p.sWb + (long)zh * p.sWh + n0 * p.ldw;

  f32x4 zero4 = {0.f, 0.f, 0.f, 0.f};
  f32x4 acc[FM][4];
#pragma unroll
  for (int fm = 0; fm < FM; ++fm)
#pragma unroll
    for (int fn = 0; fn < 4; ++fn) acc[fm][fn] = zero4;

  for (int kc = 0; kc < p.K; kc += 32) {
    uint4 areg[MT / 64], wreg[2];
#pragma unroll
    for (int i = 0; i < MT / 64; ++i) {
      int flat = tid + i * 256, r = flat >> 2, cg = flat & 3;
      areg[i] = *(const uint4*)(Ag + (long)r * p.lda + kc + cg * 8);
    }
#pragma unroll
    for (int i = 0; i < 2; ++i) {
      int flat = tid + i * 256, r = flat >> 2, cg = flat & 3;
      wreg[i] = *(const uint4*)(Wg + (long)r * p.ldw + kc + cg * 8);
    }
    __syncthreads();
#pragma unroll
    for (int i = 0; i < MT / 64; ++i) {
      int flat = tid + i * 256, r = flat >> 2, cg = flat & 3;
      *(uint4*)&Al[r * 40 + cg * 8] = areg[i];
    }
#pragma unroll
    for (int i = 0; i < 2; ++i) {
      int flat = tid + i * 256, r = flat >> 2, cg = flat & 3;
      *(uint4*)&Wl[r * 40 + cg * 8] = wreg[i];
    }
    __syncthreads();
    bf16x8 af[FM], wf[4];
#pragma unroll
    for (int fm = 0; fm < FM; ++fm)
      af[fm] = *(const bf16x8*)&Al[(wm * (MT / 2) + fm * 16 + l16) * 40 + quad * 8];
#pragma unroll
    for (int fn = 0; fn < 4; ++fn)
      wf[fn] = *(const bf16x8*)&Wl[(wn * 64 + fn * 16 + l16) * 40 + quad * 8];
#pragma unroll
    for (int fm = 0; fm < FM; ++fm)
#pragma unroll
      for (int fn = 0; fn < 4; ++fn)
        acc[fm][fn] = __builtin_amdgcn_mfma_f32_16x16x32_bf16(af[fm], wf[fn], acc[fm][fn], 0, 0, 0);
  }

  const long cOff = (long)zb * p.sCb + (long)zh * p.sCh;
  const long rOff = (long)zb * p.sRb + (long)zh * p.sRh;
#pragma unroll
  for (int fm = 0; fm < FM; ++fm) {
#pragma unroll
    for (int fn = 0; fn < 4; ++fn) {
      const long col = n0 + wn * 64 + fn * 16 + l16;
      const float bv = p.bias ? p.bias[col] : 0.f;
#pragma unroll
      for (int r = 0; r < 4; ++r) {
        const long row = m0 + wm * (MT / 2) + fm * 16 + quad * 4 + r;
        float t = acc[fm][fn][r] + bv;
        if (p.act) t = gelu_exact(t);
        t *= p.scale;
        if (p.res) t += p.res[rOff + row * p.ldr + col];
        const long ci = cOff + row * p.ldc + col;
        if (p.cBf) ((bf16_t*)p.C)[ci] = f2bf(t);
        else       ((float*)p.C)[ci] = t;
      }
    }
  }
}

// ---------------- MFMA GEMM  C = A @ B  (bf16; B staged transposed in LDS) ----------------
struct MmaNN {
  const bf16_t* A; const bf16_t* B; bf16_t* C;
  long lda, sAb, sAh;
  long ldb, sBb, sBh;
  long ldc, sCb, sCh;
  int K, zdiv;
};

template <int MT, int NTILE>
__global__ __launch_bounds__(256) void mma_nn_kernel(MmaNN p) {
  constexpr int FM = MT / 32, FN = NTILE / 32;
  __shared__ bf16_t Al[MT * 40];
  __shared__ bf16_t Bl[NTILE * 40];   // [n][k] transposed tile
  const int tid = threadIdx.x;
  const int wid = tid >> 6, lane = tid & 63;
  const int wm = wid & 1, wn = wid >> 1;
  const int quad = lane >> 4, l16 = lane & 15;
  const int z = blockIdx.z;
  const int zb = z / p.zdiv, zh = z % p.zdiv;
  const long m0 = (long)blockIdx.y * MT;
  const long n0 = (long)blockIdx.x * NTILE;
  const bf16_t* Ag = p.A + (long)zb * p.sAb + (long)zh * p.sAh + m0 * p.lda;
  const bf16_t* Bg = p.B + (long)zb * p.sBb + (long)zh * p.sBh;

  f32x4 zero4 = {0.f, 0.f, 0.f, 0.f};
  f32x4 acc[FM][FN];
#pragma unroll
  for (int fm = 0; fm < FM; ++fm)
#pragma unroll
    for (int fn = 0; fn < FN; ++fn) acc[fm][fn] = zero4;

  for (int kc = 0; kc < p.K; kc += 32) {
    uint4 areg[MT / 64], breg[NTILE / 64];
#pragma unroll
    for (int i = 0; i < MT / 64; ++i) {
      int flat = tid + i * 256, r = flat >> 2, cg = flat & 3;
      areg[i] = *(const uint4*)(Ag + (long)r * p.lda + kc + cg * 8);
    }
#pragma unroll
    for (int i = 0; i < NTILE / 64; ++i) {
      int flat = tid + i * 256;
      int k = flat / (NTILE / 8), ng = flat % (NTILE / 8);
      breg[i] = *(const uint4*)(Bg + (long)(kc + k) * p.ldb + n0 + ng * 8);
    }
    __syncthreads();
#pragma unroll
    for (int i = 0; i < MT / 64; ++i) {
      int flat = tid + i * 256, r = flat >> 2, cg = flat & 3;
      *(uint4*)&Al[r * 40 + cg * 8] = areg[i];
    }
#pragma unroll
    for (int i = 0; i < NTILE / 64; ++i) {
      int flat = tid + i * 256;
      int k = flat / (NTILE / 8), ng = flat % (NTILE / 8);
      unsigned int uu[4] = {breg[i].x, breg[i].y, breg[i].z, breg[i].w};
#pragma unroll
      for (int j = 0; j < 4; ++j) {
        Bl[(ng * 8 + 2 * j) * 40 + k]     = (bf16_t)(uu[j] & 0xffffu);
        Bl[(ng * 8 + 2 * j + 1) * 40 + k] = (bf16_t)(uu[j] >> 16);
      }
    }
    __syncthreads();
    bf16x8 af[FM], bfr[FN];
#pragma unroll
    for (int fm = 0; fm < FM; ++fm)
      af[fm] = *(const bf16x8*)&Al[(wm * (MT / 2) + fm * 16 + l16) * 40 + quad * 8];
#pragma unroll
    for (int fn = 0; fn < FN; ++fn)
      bfr[fn] = *(const bf16x8*)&Bl[(wn * (NTILE / 2) + fn * 16 + l16) * 40 + quad * 8];
#pragma unroll
    for (int fm = 0; fm < FM; ++fm)
#pragma unroll
      for (int fn = 0; fn < FN; ++fn)
        acc[fm][fn] = __builtin_amdgcn_mfma_f32_16x16x32_bf16(af[fm], bfr[fn], acc[fm][fn], 0, 0, 0);
  }

  const long cOff = (long)zb * p.sCb + (long)zh * p.sCh;
#pragma unroll
  for (int fm = 0; fm < FM; ++fm)
#pragma unroll
    for (int fn = 0; fn < FN; ++fn) {
      const long col = n0 + wn * (NTILE / 2) + fn * 16 + l16;
#pragma unroll
      for (int r = 0; r < 4; ++r) {
        const long row = m0 + wm * (MT / 2) + fm * 16 + quad * 4 + r;
        p.C[cOff + row * p.ldc + col] = f2bf(acc[fm][fn][r]);
      }
    }
}

// ---------------- softmax, 512 cols, bf16 in/out, one wave per row ----------------
__global__ __launch_bounds__(256) void softmax512_kernel(bf16_t* __restrict__ s) {
  const int w = threadIdx.x >> 6, lane = threadIdx.x & 63;
  bf16_t* p = s + ((long)blockIdx.x * 4 + w) * 512 + lane * 8;
  uint4 u = *(const uint4*)p;
  unsigned int uu[4] = {u.x, u.y, u.z, u.w};
  float v[8];
#pragma unroll
  for (int j = 0; j < 4; ++j) {
    v[2*j]   = bf2f((bf16_t)(uu[j] & 0xffffu));
    v[2*j+1] = bf2f((bf16_t)(uu[j] >> 16));
  }
  float vmax = -3.4028235e38f;
#pragma unroll
  for (int c = 0; c < 8; ++c) vmax = fmaxf(vmax, v[c]);
#pragma unroll
  for (int o = 32; o > 0; o >>= 1) vmax = fmaxf(vmax, __shfl_xor(vmax, o));
  float sum = 0.f;
#pragma unroll
  for (int c = 0; c < 8; ++c) { v[c] = __expf(v[c] - vmax); sum += v[c]; }
#pragma unroll
  for (int o = 32; o > 0; o >>= 1) sum += __shfl_xor(sum, o);
  const float inv = 1.0f / sum;
  uint4 ou;
  unsigned int* op = (unsigned int*)&ou;
#pragma unroll
  for (int j = 0; j < 4; ++j)
    op[j] = (unsigned int)f2bf(v[2*j] * inv) | ((unsigned int)f2bf(v[2*j+1] * inv) << 16);
  *(uint4*)p = ou;
}

// ---------------- softmax, 4096 cols, bf16 in/out, one block per row ----------------
__global__ __launch_bounds__(256) void softmax4096_kernel(bf16_t* __restrict__ s) {
  bf16_t* p = s + (long)blockIdx.x * 4096;
  const int tid = threadIdx.x;
  uint4 a = *(const uint4*)(p + tid * 8);
  uint4 b = *(const uint4*)(p + tid * 8 + 2048);
  unsigned int uu[8] = {a.x, a.y, a.z, a.w, b.x, b.y, b.z, b.w};
  float v[16];
#pragma unroll
  for (int j = 0; j < 8; ++j) {
    v[2*j]   = bf2f((bf16_t)(uu[j] & 0xffffu));
    v[2*j+1] = bf2f((bf16_t)(uu[j] >> 16));
  }
  float vmax = -3.4028235e38f;
#pragma unroll
  for (int c = 0; c < 16; ++c) vmax = fmaxf(vmax, v[c]);
#pragma unroll
  for (int o = 32; o > 0; o >>= 1) vmax = fmaxf(vmax, __shfl_xor(vmax, o));
  __shared__ float redm[4], reds[4];
  if ((tid & 63) == 0) redm[tid >> 6] = vmax;
  __syncthreads();
  vmax = fmaxf(fmaxf(redm[0], redm[1]), fmaxf(redm[2], redm[3]));
  float sum = 0.f;
#pragma unroll
  for (int c = 0; c < 16; ++c) { v[c] = __expf(v[c] - vmax); sum += v[c]; }
#pragma unroll
  for (int o = 32; o > 0; o >>= 1) sum += __shfl_xor(sum, o);
  if ((tid & 63) == 0) reds[tid >> 6] = sum;
  __syncthreads();
  sum = reds[0] + reds[1] + reds[2] + reds[3];
  const float inv = 1.0f / sum;
  uint4 oa, ob;
  unsigned int* oap = (unsigned int*)&oa;
  unsigned int* obp = (unsigned int*)&ob;
#pragma unroll
  for (int j = 0; j < 4; ++j)
    oap[j] = (unsigned int)f2bf(v[2*j] * inv) | ((unsigned int)f2bf(v[2*j+1] * inv) << 16);
#pragma unroll
  for (int j = 0; j < 4; ++j)
    obp[j] = (unsigned int)f2bf(v[8+2*j] * inv) | ((unsigned int)f2bf(v[8+2*j+1] * inv) << 16);
  *(uint4*)(p + tid * 8) = oa;
  *(uint4*)(p + tid * 8 + 2048) = ob;
}

// ---------------- host ----------------
#define MB(x) ((long)(x) << 20)

extern "C" void kernel_launch(void* const* d_in, const int* in_sizes, int n_in,
                              void* d_out, int out_size, void* d_ws, size_t ws_size,
                              hipStream_t stream) {
  const float* motion      = (const float*)d_in[0];
  const float* scene_feats = (const float*)d_in[2];
  const float* prior       = (const float*)d_in[3];
  const float* ln1_g = (const float*)d_in[4];
  const float* ln1_b = (const float*)d_in[5];
  const float* qkv_w = (const float*)d_in[6];
  const float* qkv_b = (const float*)d_in[7];
  const float* out_w = (const float*)d_in[8];
  const float* out_b = (const float*)d_in[9];
  const float* ln2_g = (const float*)d_in[10];
  const float* ln2_b = (const float*)d_in[11];
  const float* ff1_w = (const float*)d_in[12];
  const float* ff1_b = (const float*)d_in[13];
  const float* ff2_w = (const float*)d_in[14];
  const float* ff2_b = (const float*)d_in[15];
  const float* saq_w = (const float*)d_in[16];
  const float* saq_b = (const float*)d_in[17];
  const float* sakv_w = (const float*)d_in[18];
  const float* sakv_b = (const float*)d_in[19];
  const float* saout_w = (const float*)d_in[20];
  const float* saout_b = (const float*)d_in[21];
  const float* fc1_w = (const float*)d_in[22];
  const float* fc1_b = (const float*)d_in[23];
  const float* fc2_w = (const float*)d_in[24];
  const float* fc2_b = (const float*)d_in[25];

  char* W = (char*)d_ws;
  // buffer plan (byte offsets; lifetime overlays verified):
  bf16_t* h_bf    = (bf16_t*)(W + MB(0));    // 4 MB   dead after ff1
  float*  x_f     = (float*) (W + MB(4));    // 8 MB   dead after msca
  bf16_t* o_ff    = (bf16_t*)(W + MB(12));   // 4 MB   enc_o then ff1g
  bf16_t* qkv_bf  = (bf16_t*)(W + MB(16));   // 12 MB  dead after enc PV
  bf16_t* enc_sc  = (bf16_t*)(W + MB(28));   // 32 MB  dead after enc PV
  bf16_t* sa_sc   = (bf16_t*)(W + MB(0));    // 64 MB  overlays 0..64 (all dead by then)
  bf16_t* kv_bf   = (bf16_t*)(W + MB(64));   // 64 MB
  bf16_t* sm_bf   = (bf16_t*)(W + MB(128));  // 4 MB
  bf16_t* cat_bf  = (bf16_t*)(W + MB(132));  // 8 MB  [msca | smf]
  bf16_t* fc1g    = (bf16_t*)(W + MB(140));  // 16 MB
  bf16_t* wbase   = (bf16_t*)(W + MB(158));  // 11.5 MB bf16 weights
  bf16_t* scene_bf= (bf16_t*)(W + MB(170));  // 32 MB
  bf16_t* qsa     = (bf16_t*)(W + MB(202));  // 4 MB   (total 206 MB < 224 MiB)

  bf16_t* wq   = wbase + 0L;
  bf16_t* wout = wbase + 786432L;
  bf16_t* wff1 = wbase + 1048576L;
  bf16_t* wff2 = wbase + 1310720L;
  bf16_t* wsaq = wbase + 1572864L;
  bf16_t* wskv = wbase + 1835008L;
  bf16_t* wsout= wbase + 2359296L;
  bf16_t* wfc1 = wbase + 2621440L;
  bf16_t* wfc2 = wbase + 4718592L;

  const dim3 B256(256);
  auto cvt = [&](const float* s, bf16_t* d, long n) {
    int n4 = (int)(n / 4);
    f2bf_kernel<<<(n4 + 255) / 256, B256, 0, stream>>>((const float4*)s, (ushort4*)d, n4);
  };
  cvt(qkv_w,  wq,   786432);
  cvt(out_w,  wout, 262144);
  cvt(ff1_w,  wff1, 262144);
  cvt(ff2_w,  wff2, 262144);
  cvt(saq_w,  wsaq, 262144);
  cvt(sakv_w, wskv, 524288);
  cvt(saout_w,wsout,262144);
  cvt(fc1_w,  wfc1, 2097152);
  cvt(fc2_w,  wfc2, 1048576);
  cvt(scene_feats, scene_bf, 16777216);

  // 1. h = LN1(motion)
  ln_kernel<<<1024, B256, 0, stream>>>(motion, ln1_g, ln1_b, h_bf);

  // 2. qkv = h @ qkv_w^T + b  [4096,1536] bf16
  { MmaNT p{}; p.scale=1.f; p.zdiv=1; p.cBf=1;
    p.A=h_bf; p.lda=512; p.W=wq; p.ldw=512; p.bias=qkv_b;
    p.C=qkv_bf; p.ldc=1536; p.K=512;
    mma_nt_kernel<128><<<dim3(12,32,1), B256, 0, stream>>>(p); }

  // 3a. enc scores = q @ k^T * 0.125   z=64 (b*8+h)
  { MmaNT p{}; p.zdiv=8; p.cBf=1; p.scale=0.125f;
    p.A=qkv_bf;       p.lda=1536; p.sAb=786432; p.sAh=64;
    p.W=qkv_bf+512;   p.ldw=1536; p.sWb=786432; p.sWh=64;
    p.C=enc_sc; p.ldc=512; p.sCb=2097152; p.sCh=262144;
    p.K=64;
    mma_nt_kernel<128><<<dim3(4,4,64), B256, 0, stream>>>(p); }

  // 3b. softmax rows of 512 (64*512 rows)
  softmax512_kernel<<<8192, B256, 0, stream>>>(enc_sc);

  // 3c. enc o = P @ v   z=64
  { MmaNN p{}; p.zdiv=8;
    p.A=enc_sc; p.lda=512; p.sAb=2097152; p.sAh=262144;
    p.B=qkv_bf+1024; p.ldb=1536; p.sBb=786432; p.sBh=64;
    p.C=o_ff; p.ldc=512; p.sCb=262144; p.sCh=64;
    p.K=512;
    mma_nn_kernel<128,64><<<dim3(1,4,64), B256, 0, stream>>>(p); }

  // 4. x = motion + o @ out_w^T + b   (fp32)
  { MmaNT p{}; p.scale=1.f; p.zdiv=1;
    p.A=o_ff; p.lda=512; p.W=wout; p.ldw=512; p.bias=out_b;
    p.res=motion; p.ldr=512;
    p.C=x_f; p.ldc=512; p.K=512;
    mma_nt_kernel<64><<<dim3(4,64,1), B256, 0, stream>>>(p); }

  // 5. h2 = LN2(x)
  ln_kernel<<<1024, B256, 0, stream>>>(x_f, ln2_g, ln2_b, h_bf);

  // 6. ff1g = gelu(h2 @ ff1_w^T + b)
  { MmaNT p{}; p.scale=1.f; p.zdiv=1; p.cBf=1; p.act=1;
    p.A=h_bf; p.lda=512; p.W=wff1; p.ldw=512; p.bias=ff1_b;
    p.C=o_ff; p.ldc=512; p.K=512;
    mma_nt_kernel<64><<<dim3(4,64,1), B256, 0, stream>>>(p); }

  // 7. msca = x + ff1g @ ff2_w^T + b  -> cat[:, 0:512] bf16
  { MmaNT p{}; p.scale=1.f; p.zdiv=1; p.cBf=1;
    p.A=o_ff; p.lda=512; p.W=wff2; p.ldw=512; p.bias=ff2_b;
    p.res=x_f; p.ldr=512;
    p.C=cat_bf; p.ldc=1024; p.K=512;
    mma_nt_kernel<64><<<dim3(4,64,1), B256, 0, stream>>>(p); }

  // 8. q_sa = (msca @ saq_w^T + b) * 512^-0.5
  { MmaNT p{}; p.zdiv=1; p.cBf=1; p.scale=0.04419417382415922f;
    p.A=cat_bf; p.lda=1024; p.W=wsaq; p.ldw=512; p.bias=saq_b;
    p.C=qsa; p.ldc=512; p.K=512;
    mma_nt_kernel<64><<<dim3(4,64,1), B256, 0, stream>>>(p); }

  // 9. kv = scene @ sakv_w^T + b   [32768,1024] bf16
  { MmaNT p{}; p.scale=1.f; p.zdiv=1; p.cBf=1;
    p.A=scene_bf; p.lda=512; p.W=wskv; p.ldw=512; p.bias=sakv_b;
    p.C=kv_bf; p.ldc=1024; p.K=512;
    mma_nt_kernel<128><<<dim3(8,256,1), B256, 0, stream>>>(p); }

  // 10. semantic-aware attention: 2 chunks of 4 batches, z=16 (zb*4+zh)
  for (int c = 0; c < 2; ++c) {
    { MmaNT p{}; p.zdiv=4; p.cBf=1; p.scale=1.f;
      p.A=qsa + (long)c*4*262144;    p.lda=128;  p.sAb=262144;  p.sAh=65536;
      p.W=kv_bf + (long)c*4*4194304; p.ldw=1024; p.sWb=4194304; p.sWh=128;
      p.res=prior + (long)c*4*2097152; p.ldr=4096; p.sRb=2097152; p.sRh=0;
      p.C=sa_sc; p.ldc=4096; p.sCb=8388608; p.sCh=2097152;
      p.K=128;
      mma_nt_kernel<128><<<dim3(32,4,16), B256, 0, stream>>>(p); }
    softmax4096_kernel<<<8192, B256, 0, stream>>>(sa_sc);
    { MmaNN p{}; p.zdiv=4;
      p.A=sa_sc; p.lda=4096; p.sAb=8388608; p.sAh=2097152;
      p.B=kv_bf + (long)c*4*4194304 + 512; p.ldb=1024; p.sBb=4194304; p.sBh=128;
      p.C=sm_bf + (long)c*4*262144; p.ldc=512; p.sCb=262144; p.sCh=128;
      p.K=4096;
      mma_nn_kernel<64,128><<<dim3(1,8,16), B256, 0, stream>>>(p); }
  }

  // 11. smf = sm @ saout_w^T + b  -> cat[:, 512:1024]
  { MmaNT p{}; p.scale=1.f; p.zdiv=1; p.cBf=1;
    p.A=sm_bf; p.lda=512; p.W=wsout; p.ldw=512; p.bias=saout_b;
    p.C=cat_bf + 512; p.ldc=1024; p.K=512;
    mma_nt_kernel<64><<<dim3(4,64,1), B256, 0, stream>>>(p); }

  // 12. fc1g = gelu(cat @ fc1_w^T + b)   [4096,2048]
  { MmaNT p{}; p.scale=1.f; p.zdiv=1; p.cBf=1; p.act=1;
    p.A=cat_bf; p.lda=1024; p.W=wfc1; p.ldw=1024; p.bias=fc1_b;
    p.C=fc1g; p.ldc=2048; p.K=1024;
    mma_nt_kernel<128><<<dim3(16,32,1), B256, 0, stream>>>(p); }

  // 13. out = fc1g @ fc2_w^T + b  -> d_out fp32
  { MmaNT p{}; p.scale=1.f; p.zdiv=1;
    p.A=fc1g; p.lda=2048; p.W=wfc2; p.ldw=2048; p.bias=fc2_b;
    p.C=d_out; p.ldc=512; p.K=2048;
    mma_nt_kernel<64><<<dim3(4,64,1), B256, 0, stream>>>(p); }
}

// Round 4
// 1371.849 us; speedup vs baseline: 2.9306x; 1.0333x over previous
//
#include <hip/hip_runtime.h>

typedef unsigned short bf16_t;
typedef __attribute__((ext_vector_type(8))) short bf16x8;
typedef __attribute__((ext_vector_type(4))) float f32x4;

// ---------------- conversions ----------------
__device__ __forceinline__ float bf2f(bf16_t u) {
  union { unsigned int i; float f; } v; v.i = ((unsigned int)u) << 16; return v.f;
}
__device__ __forceinline__ bf16_t f2bf(float f) {
  union { float f; unsigned int i; } v; v.f = f;
  unsigned int u = v.i;
  u += 0x7fffu + ((u >> 16) & 1u);   // RNE
  return (bf16_t)(u >> 16);
}
__device__ __forceinline__ float gelu_exact(float x) {
  return 0.5f * x * (1.0f + erff(x * 0.7071067811865475f));
}

// ---------------- fp32 -> bf16 convert ----------------
__global__ __launch_bounds__(256) void f2bf_kernel(const float4* __restrict__ s,
                                                   ushort4* __restrict__ d, int n4) {
  int i = blockIdx.x * 256 + threadIdx.x;
  if (i < n4) {
    float4 f = s[i];
    ushort4 u; u.x = f2bf(f.x); u.y = f2bf(f.y); u.z = f2bf(f.z); u.w = f2bf(f.w);
    d[i] = u;
  }
}

// ---------------- LayerNorm: one wave per row of 512, fp32 in -> bf16 out ----------------
__global__ __launch_bounds__(256) void ln_kernel(const float* __restrict__ x,
                                                 const float* __restrict__ g,
                                                 const float* __restrict__ bta,
                                                 bf16_t* __restrict__ y) {
  const int w = threadIdx.x >> 6, lane = threadIdx.x & 63;
  const long row = (long)blockIdx.x * 4 + w;
  const long base = row * 512;
  const int c0 = lane << 2;
  float v[8];
  float4 f0 = *(const float4*)(x + base + c0);
  float4 f1 = *(const float4*)(x + base + 256 + c0);
  v[0]=f0.x; v[1]=f0.y; v[2]=f0.z; v[3]=f0.w;
  v[4]=f1.x; v[5]=f1.y; v[6]=f1.z; v[7]=f1.w;
  float s = 0.f;
#pragma unroll
  for (int c=0;c<8;++c) s += v[c];
#pragma unroll
  for (int o=32;o>0;o>>=1) s += __shfl_xor(s, o);
  const float mean = s * 0.001953125f;
  float ss = 0.f;
#pragma unroll
  for (int c=0;c<8;++c) { float d = v[c]-mean; ss += d*d; }
#pragma unroll
  for (int o=32;o>0;o>>=1) ss += __shfl_xor(ss, o);
  const float rstd = rsqrtf(ss * 0.001953125f + 1e-5f);
  ushort4 o0, o1;
  o0.x = f2bf((v[0]-mean)*rstd*g[c0+0] + bta[c0+0]);
  o0.y = f2bf((v[1]-mean)*rstd*g[c0+1] + bta[c0+1]);
  o0.z = f2bf((v[2]-mean)*rstd*g[c0+2] + bta[c0+2]);
  o0.w = f2bf((v[3]-mean)*rstd*g[c0+3] + bta[c0+3]);
  o1.x = f2bf((v[4]-mean)*rstd*g[256+c0+0] + bta[256+c0+0]);
  o1.y = f2bf((v[5]-mean)*rstd*g[256+c0+1] + bta[256+c0+1]);
  o1.z = f2bf((v[6]-mean)*rstd*g[256+c0+2] + bta[256+c0+2]);
  o1.w = f2bf((v[7]-mean)*rstd*g[256+c0+3] + bta[256+c0+3]);
  *(ushort4*)(y + base + c0) = o0;
  *(ushort4*)(y + base + 256 + c0) = o1;
}

// ---------------- MFMA GEMM  C = A @ W^T  (bf16 in, +bias/gelu/scale/+res fp32) ------------
struct MmaNT {
  const bf16_t* A; const bf16_t* W; const float* bias; const float* res; void* C;
  long lda, sAb, sAh;
  long ldw, sWb, sWh;
  long ldr, sRb, sRh;
  long ldc, sCb, sCh;
  int K, zdiv, cBf, act;
  float scale;
};

template <int MT>
__global__ __launch_bounds__(256) void mma_nt_kernel(MmaNT p) {
  constexpr int FM = MT / 32;          // m-frags per wave (wave covers MT/2 rows)
  __shared__ bf16_t Al[MT * 40];       // rows padded to 40 bf16 (80B: 16B-aligned)
  __shared__ bf16_t Wl[128 * 40];
  const int tid = threadIdx.x;
  const int wid = tid >> 6, lane = tid & 63;
  const int wm = wid & 1, wn = wid >> 1;     // waves 2x2 over (M/2, 128/2)
  const int quad = lane >> 4, l16 = lane & 15;
  const int z = blockIdx.z;
  const int zb = z / p.zdiv, zh = z % p.zdiv;
  const long m0 = (long)blockIdx.y * MT;
  const long n0 = (long)blockIdx.x * 128;
  const bf16_t* Ag = p.A + (long)zb * p.sAb + (long)zh * p.sAh + m0 * p.lda;
  const bf16_t* Wg = p.W + (long)zb * p.sWb + (long)zh * p.sWh + n0 * p.ldw;

  f32x4 zero4 = {0.f, 0.f, 0.f, 0.f};
  f32x4 acc[FM][4];
#pragma unroll
  for (int fm = 0; fm < FM; ++fm)
#pragma unroll
    for (int fn = 0; fn < 4; ++fn) acc[fm][fn] = zero4;

  for (int kc = 0; kc < p.K; kc += 32) {
    uint4 areg[MT / 64], wreg[2];
#pragma unroll
    for (int i = 0; i < MT / 64; ++i) {
      int flat = tid + i * 256, r = flat >> 2, cg = flat & 3;
      areg[i] = *(const uint4*)(Ag + (long)r * p.lda + kc + cg * 8);
    }
#pragma unroll
    for (int i = 0; i < 2; ++i) {
      int flat = tid + i * 256, r = flat >> 2, cg = flat & 3;
      wreg[i] = *(const uint4*)(Wg + (long)r * p.ldw + kc + cg * 8);
    }
    __syncthreads();
#pragma unroll
    for (int i = 0; i < MT / 64; ++i) {
      int flat = tid + i * 256, r = flat >> 2, cg = flat & 3;
      *(uint4*)&Al[r * 40 + cg * 8] = areg[i];
    }
#pragma unroll
    for (int i = 0; i < 2; ++i) {
      int flat = tid + i * 256, r = flat >> 2, cg = flat & 3;
      *(uint4*)&Wl[r * 40 + cg * 8] = wreg[i];
    }
    __syncthreads();
    bf16x8 af[FM], wf[4];
#pragma unroll
    for (int fm = 0; fm < FM; ++fm)
      af[fm] = *(const bf16x8*)&Al[(wm * (MT / 2) + fm * 16 + l16) * 40 + quad * 8];
#pragma unroll
    for (int fn = 0; fn < 4; ++fn)
      wf[fn] = *(const bf16x8*)&Wl[(wn * 64 + fn * 16 + l16) * 40 + quad * 8];
#pragma unroll
    for (int fm = 0; fm < FM; ++fm)
#pragma unroll
      for (int fn = 0; fn < 4; ++fn)
        acc[fm][fn] = __builtin_amdgcn_mfma_f32_16x16x32_bf16(af[fm], wf[fn], acc[fm][fn], 0, 0, 0);
  }

  const long cOff = (long)zb * p.sCb + (long)zh * p.sCh;
  const long rOff = (long)zb * p.sRb + (long)zh * p.sRh;
#pragma unroll
  for (int fm = 0; fm < FM; ++fm) {
#pragma unroll
    for (int fn = 0; fn < 4; ++fn) {
      const long col = n0 + wn * 64 + fn * 16 + l16;
      const float bv = p.bias ? p.bias[col] : 0.f;
#pragma unroll
      for (int r = 0; r < 4; ++r) {
        const long row = m0 + wm * (MT / 2) + fm * 16 + quad * 4 + r;
        float t = acc[fm][fn][r] + bv;
        if (p.act) t = gelu_exact(t);
        t *= p.scale;
        if (p.res) t += p.res[rOff + row * p.ldr + col];
        const long ci = cOff + row * p.ldc + col;
        if (p.cBf) ((bf16_t*)p.C)[ci] = f2bf(t);
        else       ((float*)p.C)[ci] = t;
      }
    }
  }
}

// ---------------- tile transpose: per z, [N][D] slice (ld) -> [D][N] dst ----------------
struct TransP {
  const bf16_t* src; bf16_t* dst;
  long sSb, sSh, ld;
  int nh, N, D;
};

__global__ __launch_bounds__(256) void transpose_kernel(TransP p) {
  __shared__ bf16_t T[64][72];
  const int tid = threadIdx.x;
  const int z = blockIdx.z;
  const int zb = z / p.nh, zh = z % p.nh;
  const long n0 = (long)blockIdx.x * 64;
  const long d0 = (long)blockIdx.y * 64;
  const bf16_t* src = p.src + (long)zb * p.sSb + (long)zh * p.sSh;
  bf16_t* dst = p.dst + (long)z * p.D * p.N;
#pragma unroll
  for (int i = 0; i < 2; ++i) {
    int flat = tid + i * 256, r = flat >> 3, cg = flat & 7;
    uint4 v = *(const uint4*)(src + (n0 + r) * p.ld + d0 + cg * 8);
    *(uint4*)&T[r][cg * 8] = v;
  }
  __syncthreads();
#pragma unroll
  for (int i = 0; i < 2; ++i) {
    int flat = tid + i * 256, dr = flat >> 3, ncg = flat & 7;
    uint4 o;
    unsigned int* op = (unsigned int*)&o;
#pragma unroll
    for (int j = 0; j < 4; ++j)
      op[j] = (unsigned int)T[ncg * 8 + 2 * j][dr] | ((unsigned int)T[ncg * 8 + 2 * j + 1][dr] << 16);
    *(uint4*)(dst + (d0 + dr) * p.N + n0 + ncg * 8) = o;
  }
}

// ---------------- fused flash attention ----------------
// out = softmax(scale * Q K^T + prior) V.  Q[.,DH] ldq; K[N,DH] ldk; VT[DH,N]; prior fp32 [512,N].
// grid: (1, L/64, Z); 4 waves, each 16 q-rows, KT=128 tiles over N.
struct FlashP {
  const bf16_t* Q; const bf16_t* K; const bf16_t* VT; const float* prior; bf16_t* C;
  long ldq, sQb, sQh;
  long ldk, sKb, sKh;
  long sVz, sPb;
  long ldc, sCb;
  int nh, N;
  float scale;
};

template <int DH>
__global__ __launch_bounds__(256) void flash_kernel(FlashP p) {
  constexpr int KK = DH / 32;     // k-frags over dh (QK^T)
  constexpr int NFO = DH / 16;    // output col frags
  __shared__ bf16_t Pl[4][16][136];   // per-wave P transit: 16 rows x 128 cols (pad 8)
  const int tid = threadIdx.x;
  const int w = tid >> 6, lane = tid & 63;
  const int quad = lane >> 4, l16 = lane & 15;
  const int z = blockIdx.z;
  const int zb = z / p.nh, zh = z % p.nh;
  const int qr0 = blockIdx.y * 64 + w * 16;    // wave's first q-row
  const bf16_t* Q = p.Q + (long)zb * p.sQb + (long)zh * p.sQh + (long)qr0 * p.ldq;
  const bf16_t* K = p.K + (long)zb * p.sKb + (long)zh * p.sKh;
  const bf16_t* VT = p.VT + (long)z * p.sVz;
  const float* PR = p.prior ? (p.prior + (long)zb * p.sPb + (long)qr0 * p.N) : nullptr;

  // persistent Q A-frags: lane m=l16 -> q-row, k=quad*8+j contiguous
  bf16x8 qf[KK];
#pragma unroll
  for (int kk = 0; kk < KK; ++kk)
    qf[kk] = *(const bf16x8*)(Q + (long)l16 * p.ldq + kk * 32 + quad * 8);

  f32x4 zero4 = {0.f, 0.f, 0.f, 0.f};
  f32x4 O[NFO];
#pragma unroll
  for (int f = 0; f < NFO; ++f) O[f] = zero4;
  float m_[4], l_[4];
#pragma unroll
  for (int r = 0; r < 4; ++r) { m_[r] = -1e30f; l_[r] = 0.f; }

  for (int kt = 0; kt < p.N; kt += 128) {
    // ---- S = Q K^T on this 128-col tile ----
    f32x4 s[8];
#pragma unroll
    for (int nf = 0; nf < 8; ++nf) {
      s[nf] = zero4;
#pragma unroll
      for (int kk = 0; kk < KK; ++kk) {
        bf16x8 kf = *(const bf16x8*)(K + (long)(kt + nf * 16 + l16) * p.ldk + kk * 32 + quad * 8);
        s[nf] = __builtin_amdgcn_mfma_f32_16x16x32_bf16(qf[kk], kf, s[nf], 0, 0, 0);
      }
    }
    // ---- scale + prior, tile row-max ----
    float tm[4] = {-1e30f, -1e30f, -1e30f, -1e30f};
#pragma unroll
    for (int nf = 0; nf < 8; ++nf)
#pragma unroll
      for (int r = 0; r < 4; ++r) {
        float t = s[nf][r] * p.scale;
        if (PR) t += PR[(long)(quad * 4 + r) * p.N + kt + nf * 16 + l16];
        s[nf][r] = t;
        tm[r] = fmaxf(tm[r], t);
      }
#pragma unroll
    for (int off = 1; off < 16; off <<= 1)
#pragma unroll
      for (int r = 0; r < 4; ++r) tm[r] = fmaxf(tm[r], __shfl_xor(tm[r], off));
    // ---- online softmax update ----
    float alpha[4], rs[4];
#pragma unroll
    for (int r = 0; r < 4; ++r) {
      float mn = fmaxf(m_[r], tm[r]);
      alpha[r] = __expf(m_[r] - mn);
      m_[r] = mn;
      rs[r] = 0.f;
    }
#pragma unroll
    for (int nf = 0; nf < 8; ++nf)
#pragma unroll
      for (int r = 0; r < 4; ++r) {
        float pv = __expf(s[nf][r] - m_[r]);
        s[nf][r] = pv;
        rs[r] += pv;
      }
#pragma unroll
    for (int off = 1; off < 16; off <<= 1)
#pragma unroll
      for (int r = 0; r < 4; ++r) rs[r] += __shfl_xor(rs[r], off);
#pragma unroll
    for (int r = 0; r < 4; ++r) l_[r] = l_[r] * alpha[r] + rs[r];
    // ---- P: C-layout -> LDS -> A-layout ----
#pragma unroll
    for (int nf = 0; nf < 8; ++nf)
#pragma unroll
      for (int r = 0; r < 4; ++r)
        Pl[w][quad * 4 + r][nf * 16 + l16] = f2bf(s[nf][r]);
    __syncthreads();
#pragma unroll
    for (int f = 0; f < NFO; ++f)
#pragma unroll
      for (int r = 0; r < 4; ++r) O[f][r] *= alpha[r];
    bf16x8 pf[4];
#pragma unroll
    for (int kk2 = 0; kk2 < 4; ++kk2)
      pf[kk2] = *(const bf16x8*)&Pl[w][l16][kk2 * 32 + quad * 8];
#pragma unroll
    for (int f = 0; f < NFO; ++f)
#pragma unroll
      for (int kk2 = 0; kk2 < 4; ++kk2) {
        bf16x8 vf = *(const bf16x8*)(VT + (long)(f * 16 + l16) * p.N + kt + kk2 * 32 + quad * 8);
        O[f] = __builtin_amdgcn_mfma_f32_16x16x32_bf16(pf[kk2], vf, O[f], 0, 0, 0);
      }
    __syncthreads();
  }
  // ---- epilogue: O / l, store bf16 ----
  bf16_t* Cp = p.C + (long)zb * p.sCb + (long)zh * DH;
#pragma unroll
  for (int r = 0; r < 4; ++r) l_[r] = 1.0f / l_[r];
#pragma unroll
  for (int f = 0; f < NFO; ++f)
#pragma unroll
    for (int r = 0; r < 4; ++r)
      Cp[(long)(qr0 + quad * 4 + r) * p.ldc + f * 16 + l16] = f2bf(O[f][r] * l_[r]);
}

// ---------------- host ----------------
#define MB(x) ((long)(x) << 20)

extern "C" void kernel_launch(void* const* d_in, const int* in_sizes, int n_in,
                              void* d_out, int out_size, void* d_ws, size_t ws_size,
                              hipStream_t stream) {
  const float* motion      = (const float*)d_in[0];
  const float* scene_feats = (const float*)d_in[2];
  const float* prior       = (const float*)d_in[3];
  const float* ln1_g = (const float*)d_in[4];
  const float* ln1_b = (const float*)d_in[5];
  const float* qkv_w = (const float*)d_in[6];
  const float* qkv_b = (const float*)d_in[7];
  const float* out_w = (const float*)d_in[8];
  const float* out_b = (const float*)d_in[9];
  const float* ln2_g = (const float*)d_in[10];
  const float* ln2_b = (const float*)d_in[11];
  const float* ff1_w = (const float*)d_in[12];
  const float* ff1_b = (const float*)d_in[13];
  const float* ff2_w = (const float*)d_in[14];
  const float* ff2_b = (const float*)d_in[15];
  const float* saq_w = (const float*)d_in[16];
  const float* saq_b = (const float*)d_in[17];
  const float* sakv_w = (const float*)d_in[18];
  const float* sakv_b = (const float*)d_in[19];
  const float* saout_w = (const float*)d_in[20];
  const float* saout_b = (const float*)d_in[21];
  const float* fc1_w = (const float*)d_in[22];
  const float* fc1_b = (const float*)d_in[23];
  const float* fc2_w = (const float*)d_in[24];
  const float* fc2_b = (const float*)d_in[25];

  char* W = (char*)d_ws;
  bf16_t* h_bf    = (bf16_t*)(W + MB(0));    // 4 MB
  float*  x_f     = (float*) (W + MB(4));    // 8 MB
  bf16_t* o_ff    = (bf16_t*)(W + MB(12));   // 4 MB  enc-attn out, then ff1g
  bf16_t* qkv_bf  = (bf16_t*)(W + MB(16));   // 12 MB
  bf16_t* qsa     = (bf16_t*)(W + MB(28));   // 4 MB
  bf16_t* sm_bf   = (bf16_t*)(W + MB(32));   // 4 MB
  bf16_t* cat_bf  = (bf16_t*)(W + MB(36));   // 8 MB  [msca | smf]
  bf16_t* fc1g    = (bf16_t*)(W + MB(44));   // 16 MB
  bf16_t* vTe     = (bf16_t*)(W + MB(60));   // 4 MB  enc V^T  [64 z][64][512]
  bf16_t* kv_bf   = (bf16_t*)(W + MB(64));   // 64 MB [32768][1024]
  bf16_t* vT      = (bf16_t*)(W + MB(128));  // 32 MB SA V^T  [32 z][128][4096]
  bf16_t* wbase   = (bf16_t*)(W + MB(160));  // 11.5 MB bf16 weights
  bf16_t* scene_bf= (bf16_t*)(W + MB(172));  // 32 MB  (total 204 MB)

  bf16_t* wq   = wbase + 0L;
  bf16_t* wout = wbase + 786432L;
  bf16_t* wff1 = wbase + 1048576L;
  bf16_t* wff2 = wbase + 1310720L;
  bf16_t* wsaq = wbase + 1572864L;
  bf16_t* wskv = wbase + 1835008L;
  bf16_t* wsout= wbase + 2359296L;
  bf16_t* wfc1 = wbase + 2621440L;
  bf16_t* wfc2 = wbase + 4718592L;

  const dim3 B256(256);
  auto cvt = [&](const float* s, bf16_t* d, long n) {
    int n4 = (int)(n / 4);
    f2bf_kernel<<<(n4 + 255) / 256, B256, 0, stream>>>((const float4*)s, (ushort4*)d, n4);
  };
  cvt(qkv_w,  wq,   786432);
  cvt(out_w,  wout, 262144);
  cvt(ff1_w,  wff1, 262144);
  cvt(ff2_w,  wff2, 262144);
  cvt(saq_w,  wsaq, 262144);
  cvt(sakv_w, wskv, 524288);
  cvt(saout_w,wsout,262144);
  cvt(fc1_w,  wfc1, 2097152);
  cvt(fc2_w,  wfc2, 1048576);
  cvt(scene_feats, scene_bf, 16777216);

  // 1. h = LN1(motion)
  ln_kernel<<<1024, B256, 0, stream>>>(motion, ln1_g, ln1_b, h_bf);

  // 2. qkv = h @ qkv_w^T + b  [4096,1536]
  { MmaNT p{}; p.scale=1.f; p.zdiv=1; p.cBf=1;
    p.A=h_bf; p.lda=512; p.W=wq; p.ldw=512; p.bias=qkv_b;
    p.C=qkv_bf; p.ldc=1536; p.K=512;
    mma_nt_kernel<128><<<dim3(12,32,1), B256, 0, stream>>>(p); }

  // 3. encoder attention: V^T then flash (z = b*8+h, 64)
  { TransP t{}; t.src=qkv_bf+1024; t.dst=vTe; t.sSb=786432; t.sSh=64;
    t.ld=1536; t.nh=8; t.N=512; t.D=64;
    transpose_kernel<<<dim3(8,1,64), B256, 0, stream>>>(t); }
  { FlashP p{};
    p.Q=qkv_bf;     p.ldq=1536; p.sQb=786432; p.sQh=64;
    p.K=qkv_bf+512; p.ldk=1536; p.sKb=786432; p.sKh=64;
    p.VT=vTe; p.sVz=32768;
    p.prior=nullptr; p.sPb=0;
    p.C=o_ff; p.ldc=512; p.sCb=262144;
    p.nh=8; p.N=512; p.scale=0.125f;
    flash_kernel<64><<<dim3(1,8,64), B256, 0, stream>>>(p); }

  // 4. x = motion + o @ out_w^T + b   (fp32)
  { MmaNT p{}; p.scale=1.f; p.zdiv=1;
    p.A=o_ff; p.lda=512; p.W=wout; p.ldw=512; p.bias=out_b;
    p.res=motion; p.ldr=512;
    p.C=x_f; p.ldc=512; p.K=512;
    mma_nt_kernel<64><<<dim3(4,64,1), B256, 0, stream>>>(p); }

  // 5. h2 = LN2(x)
  ln_kernel<<<1024, B256, 0, stream>>>(x_f, ln2_g, ln2_b, h_bf);

  // 6. ff1g = gelu(h2 @ ff1_w^T + b)
  { MmaNT p{}; p.scale=1.f; p.zdiv=1; p.cBf=1; p.act=1;
    p.A=h_bf; p.lda=512; p.W=wff1; p.ldw=512; p.bias=ff1_b;
    p.C=o_ff; p.ldc=512; p.K=512;
    mma_nt_kernel<64><<<dim3(4,64,1), B256, 0, stream>>>(p); }

  // 7. msca = x + ff1g @ ff2_w^T + b  -> cat[:, 0:512]
  { MmaNT p{}; p.scale=1.f; p.zdiv=1; p.cBf=1;
    p.A=o_ff; p.lda=512; p.W=wff2; p.ldw=512; p.bias=ff2_b;
    p.res=x_f; p.ldr=512;
    p.C=cat_bf; p.ldc=1024; p.K=512;
    mma_nt_kernel<64><<<dim3(4,64,1), B256, 0, stream>>>(p); }

  // 8. q_sa = (msca @ saq_w^T + b) * 512^-0.5
  { MmaNT p{}; p.zdiv=1; p.cBf=1; p.scale=0.04419417382415922f;
    p.A=cat_bf; p.lda=1024; p.W=wsaq; p.ldw=512; p.bias=saq_b;
    p.C=qsa; p.ldc=512; p.K=512;
    mma_nt_kernel<64><<<dim3(4,64,1), B256, 0, stream>>>(p); }

  // 9. kv = scene @ sakv_w^T + b   [32768,1024]
  { MmaNT p{}; p.scale=1.f; p.zdiv=1; p.cBf=1;
    p.A=scene_bf; p.lda=512; p.W=wskv; p.ldw=512; p.bias=sakv_b;
    p.C=kv_bf; p.ldc=1024; p.K=512;
    mma_nt_kernel<128><<<dim3(8,256,1), B256, 0, stream>>>(p); }

  // 10. SA attention: V^T then flash (z = b*4+h, 32), prior fused
  { TransP t{}; t.src=kv_bf+512; t.dst=vT; t.sSb=4194304; t.sSh=128;
    t.ld=1024; t.nh=4; t.N=4096; t.D=128;
    transpose_kernel<<<dim3(64,2,32), B256, 0, stream>>>(t); }
  { FlashP p{};
    p.Q=qsa;   p.ldq=128;  p.sQb=262144;  p.sQh=65536;
    p.K=kv_bf; p.ldk=1024; p.sKb=4194304; p.sKh=128;
    p.VT=vT; p.sVz=524288;
    p.prior=prior; p.sPb=2097152;
    p.C=sm_bf; p.ldc=512; p.sCb=262144;
    p.nh=4; p.N=4096; p.scale=1.f;
    flash_kernel<128><<<dim3(1,8,32), B256, 0, stream>>>(p); }

  // 11. smf = sm @ saout_w^T + b  -> cat[:, 512:1024]
  { MmaNT p{}; p.scale=1.f; p.zdiv=1; p.cBf=1;
    p.A=sm_bf; p.lda=512; p.W=wsout; p.ldw=512; p.bias=saout_b;
    p.C=cat_bf + 512; p.ldc=1024; p.K=512;
    mma_nt_kernel<64><<<dim3(4,64,1), B256, 0, stream>>>(p); }

  // 12. fc1g = gelu(cat @ fc1_w^T + b)   [4096,2048]
  { MmaNT p{}; p.scale=1.f; p.zdiv=1; p.cBf=1; p.act=1;
    p.A=cat_bf; p.lda=1024; p.W=wfc1; p.ldw=1024; p.bias=fc1_b;
    p.C=fc1g; p.ldc=2048; p.K=1024;
    mma_nt_kernel<128><<<dim3(16,32,1), B256, 0, stream>>>(p); }

  // 13. out = fc1g @ fc2_w^T + b  -> d_out fp32
  { MmaNT p{}; p.scale=1.f; p.zdiv=1;
    p.A=fc1g; p.lda=2048; p.W=wfc2; p.ldw=2048; p.bias=fc2_b;
    p.C=d_out; p.ldc=512; p.K=2048;
    mma_nt_kernel<64><<<dim3(4,64,1), B256, 0, stream>>>(p); }
}

// Round 5
// 1336.357 us; speedup vs baseline: 3.0084x; 1.0266x over previous
//
#include <hip/hip_runtime.h>

typedef unsigned short bf16_t;
typedef __attribute__((ext_vector_type(8))) short bf16x8;
typedef __attribute__((ext_vector_type(4))) float f32x4;

// ---------------- conversions ----------------
__device__ __forceinline__ float bf2f(bf16_t u) {
  union { unsigned int i; float f; } v; v.i = ((unsigned int)u) << 16; return v.f;
}
__device__ __forceinline__ bf16_t f2bf(float f) {
  union { float f; unsigned int i; } v; v.f = f;
  unsigned int u = v.i;
  u += 0x7fffu + ((u >> 16) & 1u);   // RNE
  return (bf16_t)(u >> 16);
}
__device__ __forceinline__ float gelu_exact(float x) {
  return 0.5f * x * (1.0f + erff(x * 0.7071067811865475f));
}

// ---------------- fp32 -> bf16 convert ----------------
__global__ __launch_bounds__(256) void f2bf_kernel(const float4* __restrict__ s,
                                                   ushort4* __restrict__ d, int n4) {
  int i = blockIdx.x * 256 + threadIdx.x;
  if (i < n4) {
    float4 f = s[i];
    ushort4 u; u.x = f2bf(f.x); u.y = f2bf(f.y); u.z = f2bf(f.z); u.w = f2bf(f.w);
    d[i] = u;
  }
}

// ---------------- LayerNorm: one wave per row of 512, fp32 in -> bf16 out ----------------
__global__ __launch_bounds__(256) void ln_kernel(const float* __restrict__ x,
                                                 const float* __restrict__ g,
                                                 const float* __restrict__ bta,
                                                 bf16_t* __restrict__ y) {
  const int w = threadIdx.x >> 6, lane = threadIdx.x & 63;
  const long row = (long)blockIdx.x * 4 + w;
  const long base = row * 512;
  const int c0 = lane << 2;
  float v[8];
  float4 f0 = *(const float4*)(x + base + c0);
  float4 f1 = *(const float4*)(x + base + 256 + c0);
  v[0]=f0.x; v[1]=f0.y; v[2]=f0.z; v[3]=f0.w;
  v[4]=f1.x; v[5]=f1.y; v[6]=f1.z; v[7]=f1.w;
  float s = 0.f;
#pragma unroll
  for (int c=0;c<8;++c) s += v[c];
#pragma unroll
  for (int o=32;o>0;o>>=1) s += __shfl_xor(s, o);
  const float mean = s * 0.001953125f;
  float ss = 0.f;
#pragma unroll
  for (int c=0;c<8;++c) { float d = v[c]-mean; ss += d*d; }
#pragma unroll
  for (int o=32;o>0;o>>=1) ss += __shfl_xor(ss, o);
  const float rstd = rsqrtf(ss * 0.001953125f + 1e-5f);
  ushort4 o0, o1;
  o0.x = f2bf((v[0]-mean)*rstd*g[c0+0] + bta[c0+0]);
  o0.y = f2bf((v[1]-mean)*rstd*g[c0+1] + bta[c0+1]);
  o0.z = f2bf((v[2]-mean)*rstd*g[c0+2] + bta[c0+2]);
  o0.w = f2bf((v[3]-mean)*rstd*g[c0+3] + bta[c0+3]);
  o1.x = f2bf((v[4]-mean)*rstd*g[256+c0+0] + bta[256+c0+0]);
  o1.y = f2bf((v[5]-mean)*rstd*g[256+c0+1] + bta[256+c0+1]);
  o1.z = f2bf((v[6]-mean)*rstd*g[256+c0+2] + bta[256+c0+2]);
  o1.w = f2bf((v[7]-mean)*rstd*g[256+c0+3] + bta[256+c0+3]);
  *(ushort4*)(y + base + c0) = o0;
  *(ushort4*)(y + base + 256 + c0) = o1;
}

// ---------------- MFMA GEMM  C = A @ W^T  (bf16 in, +bias/gelu/scale/+res fp32) ------------
struct MmaNT {
  const bf16_t* A; const bf16_t* W; const float* bias; const float* res; void* C;
  long lda, sAb, sAh;
  long ldw, sWb, sWh;
  long ldr, sRb, sRh;
  long ldc, sCb, sCh;
  int K, zdiv, cBf, act;
  float scale;
};

template <int MT>
__global__ __launch_bounds__(256) void mma_nt_kernel(MmaNT p) {
  constexpr int FM = MT / 32;          // m-frags per wave (wave covers MT/2 rows)
  __shared__ bf16_t Al[MT * 40];       // rows padded to 40 bf16 (80B: 16B-aligned)
  __shared__ bf16_t Wl[128 * 40];
  const int tid = threadIdx.x;
  const int wid = tid >> 6, lane = tid & 63;
  const int wm = wid & 1, wn = wid >> 1;     // waves 2x2 over (M/2, 128/2)
  const int quad = lane >> 4, l16 = lane & 15;
  const int z = blockIdx.z;
  const int zb = z / p.zdiv, zh = z % p.zdiv;
  const long m0 = (long)blockIdx.y * MT;
  const long n0 = (long)blockIdx.x * 128;
  const bf16_t* Ag = p.A + (long)zb * p.sAb + (long)zh * p.sAh + m0 * p.lda;
  const bf16_t* Wg = p.W + (long)zb * p.sWb + (long)zh * p.sWh + n0 * p.ldw;

  f32x4 zero4 = {0.f, 0.f, 0.f, 0.f};
  f32x4 acc[FM][4];
#pragma unroll
  for (int fm = 0; fm < FM; ++fm)
#pragma unroll
    for (int fn = 0; fn < 4; ++fn) acc[fm][fn] = zero4;

  for (int kc = 0; kc < p.K; kc += 32) {
    uint4 areg[MT / 64], wreg[2];
#pragma unroll
    for (int i = 0; i < MT / 64; ++i) {
      int flat = tid + i * 256, r = flat >> 2, cg = flat & 3;
      areg[i] = *(const uint4*)(Ag + (long)r * p.lda + kc + cg * 8);
    }
#pragma unroll
    for (int i = 0; i < 2; ++i) {
      int flat = tid + i * 256, r = flat >> 2, cg = flat & 3;
      wreg[i] = *(const uint4*)(Wg + (long)r * p.ldw + kc + cg * 8);
    }
    __syncthreads();
#pragma unroll
    for (int i = 0; i < MT / 64; ++i) {
      int flat = tid + i * 256, r = flat >> 2, cg = flat & 3;
      *(uint4*)&Al[r * 40 + cg * 8] = areg[i];
    }
#pragma unroll
    for (int i = 0; i < 2; ++i) {
      int flat = tid + i * 256, r = flat >> 2, cg = flat & 3;
      *(uint4*)&Wl[r * 40 + cg * 8] = wreg[i];
    }
    __syncthreads();
    bf16x8 af[FM], wf[4];
#pragma unroll
    for (int fm = 0; fm < FM; ++fm)
      af[fm] = *(const bf16x8*)&Al[(wm * (MT / 2) + fm * 16 + l16) * 40 + quad * 8];
#pragma unroll
    for (int fn = 0; fn < 4; ++fn)
      wf[fn] = *(const bf16x8*)&Wl[(wn * 64 + fn * 16 + l16) * 40 + quad * 8];
#pragma unroll
    for (int fm = 0; fm < FM; ++fm)
#pragma unroll
      for (int fn = 0; fn < 4; ++fn)
        acc[fm][fn] = __builtin_amdgcn_mfma_f32_16x16x32_bf16(af[fm], wf[fn], acc[fm][fn], 0, 0, 0);
  }

  const long cOff = (long)zb * p.sCb + (long)zh * p.sCh;
  const long rOff = (long)zb * p.sRb + (long)zh * p.sRh;
#pragma unroll
  for (int fm = 0; fm < FM; ++fm) {
#pragma unroll
    for (int fn = 0; fn < 4; ++fn) {
      const long col = n0 + wn * 64 + fn * 16 + l16;
      const float bv = p.bias ? p.bias[col] : 0.f;
#pragma unroll
      for (int r = 0; r < 4; ++r) {
        const long row = m0 + wm * (MT / 2) + fm * 16 + quad * 4 + r;
        float t = acc[fm][fn][r] + bv;
        if (p.act) t = gelu_exact(t);
        t *= p.scale;
        if (p.res) t += p.res[rOff + row * p.ldr + col];
        const long ci = cOff + row * p.ldc + col;
        if (p.cBf) ((bf16_t*)p.C)[ci] = f2bf(t);
        else       ((float*)p.C)[ci] = t;
      }
    }
  }
}

// ---------------- tile transpose: per z, [N][D] slice (ld) -> [D][N] dst ----------------
struct TransP {
  const bf16_t* src; bf16_t* dst;
  long sSb, sSh, ld;
  int nh, N, D;
};

__global__ __launch_bounds__(256) void transpose_kernel(TransP p) {
  __shared__ bf16_t T[64][72];
  const int tid = threadIdx.x;
  const int z = blockIdx.z;
  const int zb = z / p.nh, zh = z % p.nh;
  const long n0 = (long)blockIdx.x * 64;
  const long d0 = (long)blockIdx.y * 64;
  const bf16_t* src = p.src + (long)zb * p.sSb + (long)zh * p.sSh;
  bf16_t* dst = p.dst + (long)z * p.D * p.N;
#pragma unroll
  for (int i = 0; i < 2; ++i) {
    int flat = tid + i * 256, r = flat >> 3, cg = flat & 7;
    uint4 v = *(const uint4*)(src + (n0 + r) * p.ld + d0 + cg * 8);
    *(uint4*)&T[r][cg * 8] = v;
  }
  __syncthreads();
#pragma unroll
  for (int i = 0; i < 2; ++i) {
    int flat = tid + i * 256, dr = flat >> 3, ncg = flat & 7;
    uint4 o;
    unsigned int* op = (unsigned int*)&o;
#pragma unroll
    for (int j = 0; j < 4; ++j)
      op[j] = (unsigned int)T[ncg * 8 + 2 * j][dr] | ((unsigned int)T[ncg * 8 + 2 * j + 1][dr] << 16);
    *(uint4*)(dst + (d0 + dr) * p.N + n0 + ncg * 8) = o;
  }
}

// ---------------- split-KV flash attention (pass 1: per-segment partials) ----------------
// Each block: 128 q-rows (4 waves x FM=2 x 16) of one (b,h), one N-segment.
// Writes unnormalized O (fp32), and per-row (m, l) to partML.
struct FlashP2 {
  const bf16_t* Q; const bf16_t* K; const bf16_t* VT; const float* prior;
  float* partO; float* partML;
  long ldq, sQb, sQh;
  long ldk, sKb, sKh;
  long sVz, sPb;
  int nh, N, segN;
  float scale;
};

template <int DH>
__global__ __launch_bounds__(256) void flash2_kernel(FlashP2 p) {
  constexpr int KK = DH / 32;     // k-frags over dh (QK^T)
  constexpr int NFO = DH / 16;    // output col frags
  __shared__ bf16_t Pl[4][32][136];   // per-wave P transit: 32 rows x 128 cols (pad 8)
  const int tid = threadIdx.x;
  const int w = tid >> 6, lane = tid & 63;
  const int quad = lane >> 4, l16 = lane & 15;
  const int z = blockIdx.z;
  const int zb = z / p.nh, zh = z % p.nh;
  const int qr0 = blockIdx.y * 128 + w * 32;    // wave's first q-row
  const bf16_t* Q = p.Q + (long)zb * p.sQb + (long)zh * p.sQh + (long)qr0 * p.ldq;
  const bf16_t* K = p.K + (long)zb * p.sKb + (long)zh * p.sKh;
  const bf16_t* VT = p.VT + (long)z * p.sVz;

  // persistent Q A-frags (2 m-frags of 16 rows)
  bf16x8 qf[2][KK];
#pragma unroll
  for (int fm = 0; fm < 2; ++fm)
#pragma unroll
    for (int kk = 0; kk < KK; ++kk)
      qf[fm][kk] = *(const bf16x8*)(Q + (long)(fm * 16 + l16) * p.ldq + kk * 32 + quad * 8);

  f32x4 zero4 = {0.f, 0.f, 0.f, 0.f};
  f32x4 O[2][NFO];
  float m_[2][4], l_[2][4];
#pragma unroll
  for (int fm = 0; fm < 2; ++fm) {
#pragma unroll
    for (int f = 0; f < NFO; ++f) O[fm][f] = zero4;
#pragma unroll
    for (int r = 0; r < 4; ++r) { m_[fm][r] = -1e30f; l_[fm][r] = 0.f; }
  }

  const int k0 = blockIdx.x * p.segN;
  for (int kt = k0; kt < k0 + p.segN; kt += 128) {
    // ---- S = Q K^T on this 128-col tile (kf shared across both m-frags) ----
    f32x4 s[2][8];
#pragma unroll
    for (int nf = 0; nf < 8; ++nf) { s[0][nf] = zero4; s[1][nf] = zero4; }
#pragma unroll
    for (int nf = 0; nf < 8; ++nf)
#pragma unroll
      for (int kk = 0; kk < KK; ++kk) {
        bf16x8 kf = *(const bf16x8*)(K + (long)(kt + nf * 16 + l16) * p.ldk + kk * 32 + quad * 8);
        s[0][nf] = __builtin_amdgcn_mfma_f32_16x16x32_bf16(qf[0][kk], kf, s[0][nf], 0, 0, 0);
        s[1][nf] = __builtin_amdgcn_mfma_f32_16x16x32_bf16(qf[1][kk], kf, s[1][nf], 0, 0, 0);
      }
    // ---- scale + prior, tile row-max ----
    float tm[2][4];
#pragma unroll
    for (int fm = 0; fm < 2; ++fm) {
      const float* PR = p.prior ?
        (p.prior + (long)zb * p.sPb + (long)(qr0 + fm * 16 + quad * 4) * p.N) : nullptr;
#pragma unroll
      for (int r = 0; r < 4; ++r) tm[fm][r] = -1e30f;
#pragma unroll
      for (int nf = 0; nf < 8; ++nf)
#pragma unroll
        for (int r = 0; r < 4; ++r) {
          float t = s[fm][nf][r] * p.scale;
          if (PR) t += PR[(long)r * p.N + kt + nf * 16 + l16];
          s[fm][nf][r] = t;
          tm[fm][r] = fmaxf(tm[fm][r], t);
        }
    }
#pragma unroll
    for (int off = 1; off < 16; off <<= 1)
#pragma unroll
      for (int fm = 0; fm < 2; ++fm)
#pragma unroll
        for (int r = 0; r < 4; ++r) tm[fm][r] = fmaxf(tm[fm][r], __shfl_xor(tm[fm][r], off));
    // ---- online softmax update ----
    float alpha[2][4], rs[2][4];
#pragma unroll
    for (int fm = 0; fm < 2; ++fm)
#pragma unroll
      for (int r = 0; r < 4; ++r) {
        float mn = fmaxf(m_[fm][r], tm[fm][r]);
        alpha[fm][r] = __expf(m_[fm][r] - mn);
        m_[fm][r] = mn;
        rs[fm][r] = 0.f;
      }
#pragma unroll
    for (int fm = 0; fm < 2; ++fm)
#pragma unroll
      for (int nf = 0; nf < 8; ++nf)
#pragma unroll
        for (int r = 0; r < 4; ++r) {
          float pv = __expf(s[fm][nf][r] - m_[fm][r]);
          s[fm][nf][r] = pv;
          rs[fm][r] += pv;
        }
#pragma unroll
    for (int off = 1; off < 16; off <<= 1)
#pragma unroll
      for (int fm = 0; fm < 2; ++fm)
#pragma unroll
        for (int r = 0; r < 4; ++r) rs[fm][r] += __shfl_xor(rs[fm][r], off);
#pragma unroll
    for (int fm = 0; fm < 2; ++fm)
#pragma unroll
      for (int r = 0; r < 4; ++r) l_[fm][r] = l_[fm][r] * alpha[fm][r] + rs[fm][r];
    // ---- P: C-layout -> LDS -> A-layout ----
#pragma unroll
    for (int fm = 0; fm < 2; ++fm)
#pragma unroll
      for (int nf = 0; nf < 8; ++nf)
#pragma unroll
        for (int r = 0; r < 4; ++r)
          Pl[w][fm * 16 + quad * 4 + r][nf * 16 + l16] = f2bf(s[fm][nf][r]);
    __syncthreads();
#pragma unroll
    for (int fm = 0; fm < 2; ++fm)
#pragma unroll
      for (int f = 0; f < NFO; ++f)
#pragma unroll
        for (int r = 0; r < 4; ++r) O[fm][f][r] *= alpha[fm][r];
    bf16x8 pf[2][4];
#pragma unroll
    for (int fm = 0; fm < 2; ++fm)
#pragma unroll
      for (int kk2 = 0; kk2 < 4; ++kk2)
        pf[fm][kk2] = *(const bf16x8*)&Pl[w][fm * 16 + l16][kk2 * 32 + quad * 8];
#pragma unroll
    for (int f = 0; f < NFO; ++f)
#pragma unroll
      for (int kk2 = 0; kk2 < 4; ++kk2) {
        bf16x8 vf = *(const bf16x8*)(VT + (long)(f * 16 + l16) * p.N + kt + kk2 * 32 + quad * 8);
        O[0][f] = __builtin_amdgcn_mfma_f32_16x16x32_bf16(pf[0][kk2], vf, O[0][f], 0, 0, 0);
        O[1][f] = __builtin_amdgcn_mfma_f32_16x16x32_bf16(pf[1][kk2], vf, O[1][f], 0, 0, 0);
      }
    __syncthreads();
  }
  // ---- write partials ----
  const long t = ((long)z * gridDim.y + blockIdx.y) * gridDim.x + blockIdx.x;
  float* PO = p.partO + t * (128 * DH);
  float* PM = p.partML + t * 256;
#pragma unroll
  for (int fm = 0; fm < 2; ++fm) {
#pragma unroll
    for (int f = 0; f < NFO; ++f)
#pragma unroll
      for (int r = 0; r < 4; ++r)
        PO[(long)(w * 32 + fm * 16 + quad * 4 + r) * DH + f * 16 + l16] = O[fm][f][r];
    if (l16 == 0) {
#pragma unroll
      for (int r = 0; r < 4; ++r) {
        PM[(w * 32 + fm * 16 + quad * 4 + r) * 2 + 0] = m_[fm][r];
        PM[(w * 32 + fm * 16 + quad * 4 + r) * 2 + 1] = l_[fm][r];
      }
    }
  }
}

// ---------------- flash pass 2: merge NS segment partials, normalize, store bf16 ----------
struct MergeP {
  const float* partO; const float* partML; bf16_t* C;
  long ldc, sCb;
  int nh, y;
};

template <int DH, int NS>
__global__ __launch_bounds__(256) void fmerge_kernel(MergeP p) {
  const int tid = threadIdx.x;
  const int r = tid >> 1, ch = tid & 1;          // 128 rows x 2 col-halves
  const int blk = blockIdx.x;
  const int z = blk / p.y, qb = blk % p.y;
  const int zb = z / p.nh, zh = z % p.nh;
  const long t0 = (long)blk * NS;
  float mm[NS], wgt[NS];
  float mstar = -1e30f;
#pragma unroll
  for (int s = 0; s < NS; ++s) {
    mm[s] = p.partML[(t0 + s) * 256 + r * 2];
    mstar = fmaxf(mstar, mm[s]);
  }
  float lsum = 0.f;
#pragma unroll
  for (int s = 0; s < NS; ++s) {
    wgt[s] = __expf(mm[s] - mstar);
    lsum += wgt[s] * p.partML[(t0 + s) * 256 + r * 2 + 1];
  }
  const float inv = 1.0f / lsum;
  const int c0 = ch * (DH / 2);
  bf16_t* Cp = p.C + (long)zb * p.sCb + (long)(qb * 128 + r) * p.ldc + (long)zh * DH + c0;
#pragma unroll
  for (int c = 0; c < DH / 2; c += 4) {
    float4 acc = make_float4(0.f, 0.f, 0.f, 0.f);
#pragma unroll
    for (int s = 0; s < NS; ++s) {
      float4 v = *(const float4*)(p.partO + (t0 + s) * (128 * DH) + (long)r * DH + c0 + c);
      acc.x += wgt[s] * v.x; acc.y += wgt[s] * v.y;
      acc.z += wgt[s] * v.z; acc.w += wgt[s] * v.w;
    }
    ushort4 o;
    o.x = f2bf(acc.x * inv); o.y = f2bf(acc.y * inv);
    o.z = f2bf(acc.z * inv); o.w = f2bf(acc.w * inv);
    *(ushort4*)(Cp + c) = o;
  }
}

// ---------------- host ----------------
#define MB(x) ((long)(x) << 20)

extern "C" void kernel_launch(void* const* d_in, const int* in_sizes, int n_in,
                              void* d_out, int out_size, void* d_ws, size_t ws_size,
                              hipStream_t stream) {
  const float* motion      = (const float*)d_in[0];
  const float* scene_feats = (const float*)d_in[2];
  const float* prior       = (const float*)d_in[3];
  const float* ln1_g = (const float*)d_in[4];
  const float* ln1_b = (const float*)d_in[5];
  const float* qkv_w = (const float*)d_in[6];
  const float* qkv_b = (const float*)d_in[7];
  const float* out_w = (const float*)d_in[8];
  const float* out_b = (const float*)d_in[9];
  const float* ln2_g = (const float*)d_in[10];
  const float* ln2_b = (const float*)d_in[11];
  const float* ff1_w = (const float*)d_in[12];
  const float* ff1_b = (const float*)d_in[13];
  const float* ff2_w = (const float*)d_in[14];
  const float* ff2_b = (const float*)d_in[15];
  const float* saq_w = (const float*)d_in[16];
  const float* saq_b = (const float*)d_in[17];
  const float* sakv_w = (const float*)d_in[18];
  const float* sakv_b = (const float*)d_in[19];
  const float* saout_w = (const float*)d_in[20];
  const float* saout_b = (const float*)d_in[21];
  const float* fc1_w = (const float*)d_in[22];
  const float* fc1_b = (const float*)d_in[23];
  const float* fc2_w = (const float*)d_in[24];
  const float* fc2_b = (const float*)d_in[25];

  char* W = (char*)d_ws;
  bf16_t* h_bf    = (bf16_t*)(W + MB(0));    // 4 MB
  float*  x_f     = (float*) (W + MB(4));    // 8 MB
  bf16_t* o_ff    = (bf16_t*)(W + MB(12));   // 4 MB  enc-attn out, then ff1g
  bf16_t* qkv_bf  = (bf16_t*)(W + MB(16));   // 12 MB
  bf16_t* qsa     = (bf16_t*)(W + MB(28));   // 4 MB
  bf16_t* sm_bf   = (bf16_t*)(W + MB(32));   // 4 MB
  bf16_t* cat_bf  = (bf16_t*)(W + MB(36));   // 8 MB  [msca | smf]; pre-enc: enc partML
  bf16_t* fc1g    = (bf16_t*)(W + MB(44));   // 16 MB; pre-fc1: enc partO
  bf16_t* vTe     = (bf16_t*)(W + MB(60));   // 4 MB  enc V^T; post-enc: SA partML
  bf16_t* kv_bf   = (bf16_t*)(W + MB(64));   // 64 MB [32768][1024]
  bf16_t* vT      = (bf16_t*)(W + MB(128));  // 32 MB SA V^T  [32 z][128][4096]
  bf16_t* wbase   = (bf16_t*)(W + MB(160));  // 11.5 MB bf16 weights
  bf16_t* scene_bf= (bf16_t*)(W + MB(172));  // 32 MB; post-kv: SA partO (32 MB)

  float* encO  = (float*)fc1g;               // 16 MB (64z*4y*2s tiles x 128x64 f32)
  float* encML = (float*)cat_bf;             // 0.5 MB
  float* saO   = (float*)scene_bf;           // 32 MB (32z*4y*4s tiles x 128x128 f32)
  float* saML  = (float*)vTe;                // 0.5 MB

  bf16_t* wq   = wbase + 0L;
  bf16_t* wout = wbase + 786432L;
  bf16_t* wff1 = wbase + 1048576L;
  bf16_t* wff2 = wbase + 1310720L;
  bf16_t* wsaq = wbase + 1572864L;
  bf16_t* wskv = wbase + 1835008L;
  bf16_t* wsout= wbase + 2359296L;
  bf16_t* wfc1 = wbase + 2621440L;
  bf16_t* wfc2 = wbase + 4718592L;

  const dim3 B256(256);
  auto cvt = [&](const float* s, bf16_t* d, long n) {
    int n4 = (int)(n / 4);
    f2bf_kernel<<<(n4 + 255) / 256, B256, 0, stream>>>((const float4*)s, (ushort4*)d, n4);
  };
  cvt(qkv_w,  wq,   786432);
  cvt(out_w,  wout, 262144);
  cvt(ff1_w,  wff1, 262144);
  cvt(ff2_w,  wff2, 262144);
  cvt(saq_w,  wsaq, 262144);
  cvt(sakv_w, wskv, 524288);
  cvt(saout_w,wsout,262144);
  cvt(fc1_w,  wfc1, 2097152);
  cvt(fc2_w,  wfc2, 1048576);
  cvt(scene_feats, scene_bf, 16777216);

  // 1. h = LN1(motion)
  ln_kernel<<<1024, B256, 0, stream>>>(motion, ln1_g, ln1_b, h_bf);

  // 2. qkv = h @ qkv_w^T + b  [4096,1536]
  { MmaNT p{}; p.scale=1.f; p.zdiv=1; p.cBf=1;
    p.A=h_bf; p.lda=512; p.W=wq; p.ldw=512; p.bias=qkv_b;
    p.C=qkv_bf; p.ldc=1536; p.K=512;
    mma_nt_kernel<128><<<dim3(12,32,1), B256, 0, stream>>>(p); }

  // 3. encoder attention: V^T -> split flash (NS=2) -> merge
  { TransP t{}; t.src=qkv_bf+1024; t.dst=vTe; t.sSb=786432; t.sSh=64;
    t.ld=1536; t.nh=8; t.N=512; t.D=64;
    transpose_kernel<<<dim3(8,1,64), B256, 0, stream>>>(t); }
  { FlashP2 p{};
    p.Q=qkv_bf;     p.ldq=1536; p.sQb=786432; p.sQh=64;
    p.K=qkv_bf+512; p.ldk=1536; p.sKb=786432; p.sKh=64;
    p.VT=vTe; p.sVz=32768;
    p.prior=nullptr; p.sPb=0;
    p.partO=encO; p.partML=encML;
    p.nh=8; p.N=512; p.segN=256; p.scale=0.125f;
    flash2_kernel<64><<<dim3(2,4,64), B256, 0, stream>>>(p); }
  { MergeP m{}; m.partO=encO; m.partML=encML; m.C=o_ff;
    m.ldc=512; m.sCb=262144; m.nh=8; m.y=4;
    fmerge_kernel<64,2><<<256, B256, 0, stream>>>(m); }

  // 4. x = motion + o @ out_w^T + b   (fp32)
  { MmaNT p{}; p.scale=1.f; p.zdiv=1;
    p.A=o_ff; p.lda=512; p.W=wout; p.ldw=512; p.bias=out_b;
    p.res=motion; p.ldr=512;
    p.C=x_f; p.ldc=512; p.K=512;
    mma_nt_kernel<64><<<dim3(4,64,1), B256, 0, stream>>>(p); }

  // 5. h2 = LN2(x)
  ln_kernel<<<1024, B256, 0, stream>>>(x_f, ln2_g, ln2_b, h_bf);

  // 6. ff1g = gelu(h2 @ ff1_w^T + b)
  { MmaNT p{}; p.scale=1.f; p.zdiv=1; p.cBf=1; p.act=1;
    p.A=h_bf; p.lda=512; p.W=wff1; p.ldw=512; p.bias=ff1_b;
    p.C=o_ff; p.ldc=512; p.K=512;
    mma_nt_kernel<64><<<dim3(4,64,1), B256, 0, stream>>>(p); }

  // 7. msca = x + ff1g @ ff2_w^T + b  -> cat[:, 0:512]
  { MmaNT p{}; p.scale=1.f; p.zdiv=1; p.cBf=1;
    p.A=o_ff; p.lda=512; p.W=wff2; p.ldw=512; p.bias=ff2_b;
    p.res=x_f; p.ldr=512;
    p.C=cat_bf; p.ldc=1024; p.K=512;
    mma_nt_kernel<64><<<dim3(4,64,1), B256, 0, stream>>>(p); }

  // 8. q_sa = (msca @ saq_w^T + b) * 512^-0.5
  { MmaNT p{}; p.zdiv=1; p.cBf=1; p.scale=0.04419417382415922f;
    p.A=cat_bf; p.lda=1024; p.W=wsaq; p.ldw=512; p.bias=saq_b;
    p.C=qsa; p.ldc=512; p.K=512;
    mma_nt_kernel<64><<<dim3(4,64,1), B256, 0, stream>>>(p); }

  // 9. kv = scene @ sakv_w^T + b   [32768,1024]
  { MmaNT p{}; p.scale=1.f; p.zdiv=1; p.cBf=1;
    p.A=scene_bf; p.lda=512; p.W=wskv; p.ldw=512; p.bias=sakv_b;
    p.C=kv_bf; p.ldc=1024; p.K=512;
    mma_nt_kernel<128><<<dim3(8,256,1), B256, 0, stream>>>(p); }

  // 10. SA attention: V^T -> split flash (NS=4, prior fused) -> merge
  { TransP t{}; t.src=kv_bf+512; t.dst=vT; t.sSb=4194304; t.sSh=128;
    t.ld=1024; t.nh=4; t.N=4096; t.D=128;
    transpose_kernel<<<dim3(64,2,32), B256, 0, stream>>>(t); }
  { FlashP2 p{};
    p.Q=qsa;   p.ldq=128;  p.sQb=262144;  p.sQh=65536;
    p.K=kv_bf; p.ldk=1024; p.sKb=4194304; p.sKh=128;
    p.VT=vT; p.sVz=524288;
    p.prior=prior; p.sPb=2097152;
    p.partO=saO; p.partML=saML;
    p.nh=4; p.N=4096; p.segN=1024; p.scale=1.f;
    flash2_kernel<128><<<dim3(4,4,32), B256, 0, stream>>>(p); }
  { MergeP m{}; m.partO=saO; m.partML=saML; m.C=sm_bf;
    m.ldc=512; m.sCb=262144; m.nh=4; m.y=4;
    fmerge_kernel<128,4><<<128, B256, 0, stream>>>(m); }

  // 11. smf = sm @ saout_w^T + b  -> cat[:, 512:1024]
  { MmaNT p{}; p.scale=1.f; p.zdiv=1; p.cBf=1;
    p.A=sm_bf; p.lda=512; p.W=wsout; p.ldw=512; p.bias=saout_b;
    p.C=cat_bf + 512; p.ldc=1024; p.K=512;
    mma_nt_kernel<64><<<dim3(4,64,1), B256, 0, stream>>>(p); }

  // 12. fc1g = gelu(cat @ fc1_w^T + b)   [4096,2048]
  { MmaNT p{}; p.scale=1.f; p.zdiv=1; p.cBf=1; p.act=1;
    p.A=cat_bf; p.lda=1024; p.W=wfc1; p.ldw=1024; p.bias=fc1_b;
    p.C=fc1g; p.ldc=2048; p.K=1024;
    mma_nt_kernel<128><<<dim3(16,32,1), B256, 0, stream>>>(p); }

  // 13. out = fc1g @ fc2_w^T + b  -> d_out fp32
  { MmaNT p{}; p.scale=1.f; p.zdiv=1;
    p.A=fc1g; p.lda=2048; p.W=wfc2; p.ldw=2048; p.bias=fc2_b;
    p.C=d_out; p.ldc=512; p.K=2048;
    mma_nt_kernel<64><<<dim3(4,64,1), B256, 0, stream>>>(p); }
}

// Round 6
// 919.577 us; speedup vs baseline: 4.3720x; 1.4532x over previous
//
#include <hip/hip_runtime.h>

typedef unsigned short bf16_t;
typedef __attribute__((ext_vector_type(8))) short bf16x8;
typedef __attribute__((ext_vector_type(4))) float f32x4;

// ---------------- conversions ----------------
__device__ __forceinline__ float bf2f(bf16_t u) {
  union { unsigned int i; float f; } v; v.i = ((unsigned int)u) << 16; return v.f;
}
__device__ __forceinline__ bf16_t f2bf(float f) {
  union { float f; unsigned int i; } v; v.f = f;
  unsigned int u = v.i;
  u += 0x7fffu + ((u >> 16) & 1u);   // RNE
  return (bf16_t)(u >> 16);
}
__device__ __forceinline__ float gelu_exact(float x) {
  return 0.5f * x * (1.0f + erff(x * 0.7071067811865475f));
}

// ---------------- fp32 -> bf16 convert ----------------
__global__ __launch_bounds__(256) void f2bf_kernel(const float4* __restrict__ s,
                                                   ushort4* __restrict__ d, int n4) {
  int i = blockIdx.x * 256 + threadIdx.x;
  if (i < n4) {
    float4 f = s[i];
    ushort4 u; u.x = f2bf(f.x); u.y = f2bf(f.y); u.z = f2bf(f.z); u.w = f2bf(f.w);
    d[i] = u;
  }
}

// ---------------- LayerNorm: one wave per row of 512, fp32 in -> bf16 out ----------------
__global__ __launch_bounds__(256) void ln_kernel(const float* __restrict__ x,
                                                 const float* __restrict__ g,
                                                 const float* __restrict__ bta,
                                                 bf16_t* __restrict__ y) {
  const int w = threadIdx.x >> 6, lane = threadIdx.x & 63;
  const long row = (long)blockIdx.x * 4 + w;
  const long base = row * 512;
  const int c0 = lane << 2;
  float v[8];
  float4 f0 = *(const float4*)(x + base + c0);
  float4 f1 = *(const float4*)(x + base + 256 + c0);
  v[0]=f0.x; v[1]=f0.y; v[2]=f0.z; v[3]=f0.w;
  v[4]=f1.x; v[5]=f1.y; v[6]=f1.z; v[7]=f1.w;
  float s = 0.f;
#pragma unroll
  for (int c=0;c<8;++c) s += v[c];
#pragma unroll
  for (int o=32;o>0;o>>=1) s += __shfl_xor(s, o);
  const float mean = s * 0.001953125f;
  float ss = 0.f;
#pragma unroll
  for (int c=0;c<8;++c) { float d = v[c]-mean; ss += d*d; }
#pragma unroll
  for (int o=32;o>0;o>>=1) ss += __shfl_xor(ss, o);
  const float rstd = rsqrtf(ss * 0.001953125f + 1e-5f);
  ushort4 o0, o1;
  o0.x = f2bf((v[0]-mean)*rstd*g[c0+0] + bta[c0+0]);
  o0.y = f2bf((v[1]-mean)*rstd*g[c0+1] + bta[c0+1]);
  o0.z = f2bf((v[2]-mean)*rstd*g[c0+2] + bta[c0+2]);
  o0.w = f2bf((v[3]-mean)*rstd*g[c0+3] + bta[c0+3]);
  o1.x = f2bf((v[4]-mean)*rstd*g[256+c0+0] + bta[256+c0+0]);
  o1.y = f2bf((v[5]-mean)*rstd*g[256+c0+1] + bta[256+c0+1]);
  o1.z = f2bf((v[6]-mean)*rstd*g[256+c0+2] + bta[256+c0+2]);
  o1.w = f2bf((v[7]-mean)*rstd*g[256+c0+3] + bta[256+c0+3]);
  *(ushort4*)(y + base + c0) = o0;
  *(ushort4*)(y + base + 256 + c0) = o1;
}

// ---------------- MFMA GEMM  C = A @ W^T  (bf16 in, +bias/gelu/scale/+res fp32) ------------
struct MmaNT {
  const bf16_t* A; const bf16_t* W; const float* bias; const float* res; void* C;
  long lda, sAb, sAh;
  long ldw, sWb, sWh;
  long ldr, sRb, sRh;
  long ldc, sCb, sCh;
  int K, zdiv, cBf, act;
  float scale;
};

template <int MT>
__global__ __launch_bounds__(256) void mma_nt_kernel(MmaNT p) {
  constexpr int FM = MT / 32;          // m-frags per wave (wave covers MT/2 rows)
  __shared__ bf16_t Al[MT * 40];       // rows padded to 40 bf16 (80B: 16B-aligned)
  __shared__ bf16_t Wl[128 * 40];
  const int tid = threadIdx.x;
  const int wid = tid >> 6, lane = tid & 63;
  const int wm = wid & 1, wn = wid >> 1;     // waves 2x2 over (M/2, 128/2)
  const int quad = lane >> 4, l16 = lane & 15;
  const int z = blockIdx.z;
  const int zb = z / p.zdiv, zh = z % p.zdiv;
  const long m0 = (long)blockIdx.y * MT;
  const long n0 = (long)blockIdx.x * 128;
  const bf16_t* Ag = p.A + (long)zb * p.sAb + (long)zh * p.sAh + m0 * p.lda;
  const bf16_t* Wg = p.W + (long)zb * p.sWb + (long)zh * p.sWh + n0 * p.ldw;

  f32x4 zero4 = {0.f, 0.f, 0.f, 0.f};
  f32x4 acc[FM][4];
#pragma unroll
  for (int fm = 0; fm < FM; ++fm)
#pragma unroll
    for (int fn = 0; fn < 4; ++fn) acc[fm][fn] = zero4;

  for (int kc = 0; kc < p.K; kc += 32) {
    uint4 areg[MT / 64], wreg[2];
#pragma unroll
    for (int i = 0; i < MT / 64; ++i) {
      int flat = tid + i * 256, r = flat >> 2, cg = flat & 3;
      areg[i] = *(const uint4*)(Ag + (long)r * p.lda + kc + cg * 8);
    }
#pragma unroll
    for (int i = 0; i < 2; ++i) {
      int flat = tid + i * 256, r = flat >> 2, cg = flat & 3;
      wreg[i] = *(const uint4*)(Wg + (long)r * p.ldw + kc + cg * 8);
    }
    __syncthreads();
#pragma unroll
    for (int i = 0; i < MT / 64; ++i) {
      int flat = tid + i * 256, r = flat >> 2, cg = flat & 3;
      *(uint4*)&Al[r * 40 + cg * 8] = areg[i];
    }
#pragma unroll
    for (int i = 0; i < 2; ++i) {
      int flat = tid + i * 256, r = flat >> 2, cg = flat & 3;
      *(uint4*)&Wl[r * 40 + cg * 8] = wreg[i];
    }
    __syncthreads();
    bf16x8 af[FM], wf[4];
#pragma unroll
    for (int fm = 0; fm < FM; ++fm)
      af[fm] = *(const bf16x8*)&Al[(wm * (MT / 2) + fm * 16 + l16) * 40 + quad * 8];
#pragma unroll
    for (int fn = 0; fn < 4; ++fn)
      wf[fn] = *(const bf16x8*)&Wl[(wn * 64 + fn * 16 + l16) * 40 + quad * 8];
#pragma unroll
    for (int fm = 0; fm < FM; ++fm)
#pragma unroll
      for (int fn = 0; fn < 4; ++fn)
        acc[fm][fn] = __builtin_amdgcn_mfma_f32_16x16x32_bf16(af[fm], wf[fn], acc[fm][fn], 0, 0, 0);
  }

  const long cOff = (long)zb * p.sCb + (long)zh * p.sCh;
  const long rOff = (long)zb * p.sRb + (long)zh * p.sRh;
#pragma unroll
  for (int fm = 0; fm < FM; ++fm) {
#pragma unroll
    for (int fn = 0; fn < 4; ++fn) {
      const long col = n0 + wn * 64 + fn * 16 + l16;
      const float bv = p.bias ? p.bias[col] : 0.f;
#pragma unroll
      for (int r = 0; r < 4; ++r) {
        const long row = m0 + wm * (MT / 2) + fm * 16 + quad * 4 + r;
        float t = acc[fm][fn][r] + bv;
        if (p.act) t = gelu_exact(t);
        t *= p.scale;
        if (p.res) t += p.res[rOff + row * p.ldr + col];
        const long ci = cOff + row * p.ldc + col;
        if (p.cBf) ((bf16_t*)p.C)[ci] = f2bf(t);
        else       ((float*)p.C)[ci] = t;
      }
    }
  }
}

// ---------------- tile transpose: per z, [N][D] slice (ld) -> [D][N] dst ----------------
struct TransP {
  const bf16_t* src; bf16_t* dst;
  long sSb, sSh, ld;
  int nh, N, D;
};

__global__ __launch_bounds__(256) void transpose_kernel(TransP p) {
  __shared__ bf16_t T[64][72];
  const int tid = threadIdx.x;
  const int z = blockIdx.z;
  const int zb = z / p.nh, zh = z % p.nh;
  const long n0 = (long)blockIdx.x * 64;
  const long d0 = (long)blockIdx.y * 64;
  const bf16_t* src = p.src + (long)zb * p.sSb + (long)zh * p.sSh;
  bf16_t* dst = p.dst + (long)z * p.D * p.N;
#pragma unroll
  for (int i = 0; i < 2; ++i) {
    int flat = tid + i * 256, r = flat >> 3, cg = flat & 7;
    uint4 v = *(const uint4*)(src + (n0 + r) * p.ld + d0 + cg * 8);
    *(uint4*)&T[r][cg * 8] = v;
  }
  __syncthreads();
#pragma unroll
  for (int i = 0; i < 2; ++i) {
    int flat = tid + i * 256, dr = flat >> 3, ncg = flat & 7;
    uint4 o;
    unsigned int* op = (unsigned int*)&o;
#pragma unroll
    for (int j = 0; j < 4; ++j)
      op[j] = (unsigned int)T[ncg * 8 + 2 * j][dr] | ((unsigned int)T[ncg * 8 + 2 * j + 1][dr] << 16);
    *(uint4*)(dst + (d0 + dr) * p.N + n0 + ncg * 8) = o;
  }
}

// ---------------- split-KV flash attention, LDS-staged (pass 1) ----------------
// Block: 128 q-rows (4 waves x FM=2 x 16) of one (b,h), one N-segment; k-tile = 64 N-rows.
// K/VT tiles cooperatively staged coalesced into LDS; fragments read from LDS.
struct FlashP2 {
  const bf16_t* Q; const bf16_t* K; const bf16_t* VT; const float* prior;
  float* partO; float* partML;
  long ldq, sQb, sQh;
  long ldk, sKb, sKh;
  long sVz, sPb;
  int nh, N, segN;
  float scale;
};

template <int DH, int HASP>
__global__ __launch_bounds__(256) void flash3_kernel(FlashP2 p) {
  constexpr int KK = DH / 32;       // k-frags over dh (QK^T)
  constexpr int NFO = DH / 16;      // output col frags
  constexpr int KPAD = DH + 8;
  __shared__ bf16_t Kl[64 * KPAD];  // K tile   [64 n-rows][DH]
  __shared__ bf16_t Vl[DH * 72];    // VT tile  [DH rows][64 n-cols]
  __shared__ bf16_t Pl[128 * 72];   // P transit [128 q-rows][64]
  const int tid = threadIdx.x;
  const int w = tid >> 6, lane = tid & 63;
  const int quad = lane >> 4, l16 = lane & 15;
  const int z = blockIdx.z;
  const int zb = z / p.nh, zh = z % p.nh;
  const int qr0 = blockIdx.y * 128 + w * 32;    // wave's first q-row
  const bf16_t* Q = p.Q + (long)zb * p.sQb + (long)zh * p.sQh + (long)qr0 * p.ldq;
  const bf16_t* K = p.K + (long)zb * p.sKb + (long)zh * p.sKh;
  const bf16_t* VT = p.VT + (long)z * p.sVz;

  // persistent Q A-frags (2 m-frags of 16 rows)
  bf16x8 qf[2][KK];
#pragma unroll
  for (int fm = 0; fm < 2; ++fm)
#pragma unroll
    for (int kk = 0; kk < KK; ++kk)
      qf[fm][kk] = *(const bf16x8*)(Q + (long)(fm * 16 + l16) * p.ldq + kk * 32 + quad * 8);

  f32x4 zero4 = {0.f, 0.f, 0.f, 0.f};
  f32x4 O[2][NFO];
  float m_[2][4], l_[2][4];
#pragma unroll
  for (int fm = 0; fm < 2; ++fm) {
#pragma unroll
    for (int f = 0; f < NFO; ++f) O[fm][f] = zero4;
#pragma unroll
    for (int r = 0; r < 4; ++r) { m_[fm][r] = -1e30f; l_[fm][r] = 0.f; }
  }

  const int k0 = blockIdx.x * p.segN;
  for (int kt = k0; kt < k0 + p.segN; kt += 64) {
    __syncthreads();   // prior iteration's LDS reads complete
    // ---- stage K tile: 64 rows x DH cols, coalesced uint4 ----
    constexpr int KTH = DH / 8;          // threads per K row
#pragma unroll
    for (int i = 0; i < DH / 32; ++i) {
      int flat = tid + i * 256, r = flat / KTH, c = (flat % KTH) * 8;
      *(uint4*)&Kl[r * KPAD + c] = *(const uint4*)(K + (long)(kt + r) * p.ldk + c);
    }
    // ---- stage VT tile: DH rows x 64 cols ----
#pragma unroll
    for (int i = 0; i < DH / 32; ++i) {
      int flat = tid + i * 256, r = flat >> 3, c = (flat & 7) * 8;
      *(uint4*)&Vl[r * 72 + c] = *(const uint4*)(VT + (long)r * p.N + kt + c);
    }
    // ---- prefetch prior (fp32, direct; latency overlaps QK^T MFMAs) ----
    float pr[2][4][4];
    if (HASP) {
#pragma unroll
      for (int fm = 0; fm < 2; ++fm) {
        const float* PR = p.prior + (long)zb * p.sPb +
                          (long)(qr0 + fm * 16 + quad * 4) * p.N + kt;
#pragma unroll
        for (int nf = 0; nf < 4; ++nf)
#pragma unroll
          for (int r = 0; r < 4; ++r)
            pr[fm][nf][r] = PR[(long)r * p.N + nf * 16 + l16];
      }
    }
    __syncthreads();
    // ---- S = Q K^T on this 64-col tile (kf from LDS, shared by all waves) ----
    f32x4 s[2][4];
#pragma unroll
    for (int nf = 0; nf < 4; ++nf) { s[0][nf] = zero4; s[1][nf] = zero4; }
#pragma unroll
    for (int nf = 0; nf < 4; ++nf)
#pragma unroll
      for (int kk = 0; kk < KK; ++kk) {
        bf16x8 kf = *(const bf16x8*)&Kl[(nf * 16 + l16) * KPAD + kk * 32 + quad * 8];
        s[0][nf] = __builtin_amdgcn_mfma_f32_16x16x32_bf16(qf[0][kk], kf, s[0][nf], 0, 0, 0);
        s[1][nf] = __builtin_amdgcn_mfma_f32_16x16x32_bf16(qf[1][kk], kf, s[1][nf], 0, 0, 0);
      }
    // ---- scale + prior, tile row-max ----
    float tm[2][4];
#pragma unroll
    for (int fm = 0; fm < 2; ++fm) {
#pragma unroll
      for (int r = 0; r < 4; ++r) tm[fm][r] = -1e30f;
#pragma unroll
      for (int nf = 0; nf < 4; ++nf)
#pragma unroll
        for (int r = 0; r < 4; ++r) {
          float t = s[fm][nf][r] * p.scale;
          if (HASP) t += pr[fm][nf][r];
          s[fm][nf][r] = t;
          tm[fm][r] = fmaxf(tm[fm][r], t);
        }
    }
#pragma unroll
    for (int off = 1; off < 16; off <<= 1)
#pragma unroll
      for (int fm = 0; fm < 2; ++fm)
#pragma unroll
        for (int r = 0; r < 4; ++r) tm[fm][r] = fmaxf(tm[fm][r], __shfl_xor(tm[fm][r], off));
    // ---- online softmax update ----
    float alpha[2][4], rs[2][4];
#pragma unroll
    for (int fm = 0; fm < 2; ++fm)
#pragma unroll
      for (int r = 0; r < 4; ++r) {
        float mn = fmaxf(m_[fm][r], tm[fm][r]);
        alpha[fm][r] = __expf(m_[fm][r] - mn);
        m_[fm][r] = mn;
        rs[fm][r] = 0.f;
      }
#pragma unroll
    for (int fm = 0; fm < 2; ++fm)
#pragma unroll
      for (int nf = 0; nf < 4; ++nf)
#pragma unroll
        for (int r = 0; r < 4; ++r) {
          float pv = __expf(s[fm][nf][r] - m_[fm][r]);
          s[fm][nf][r] = pv;
          rs[fm][r] += pv;
        }
#pragma unroll
    for (int off = 1; off < 16; off <<= 1)
#pragma unroll
      for (int fm = 0; fm < 2; ++fm)
#pragma unroll
        for (int r = 0; r < 4; ++r) rs[fm][r] += __shfl_xor(rs[fm][r], off);
#pragma unroll
    for (int fm = 0; fm < 2; ++fm)
#pragma unroll
      for (int r = 0; r < 4; ++r) l_[fm][r] = l_[fm][r] * alpha[fm][r] + rs[fm][r];
    // ---- P: C-layout -> LDS (own rows) -> A-layout ----
#pragma unroll
    for (int fm = 0; fm < 2; ++fm)
#pragma unroll
      for (int nf = 0; nf < 4; ++nf)
#pragma unroll
        for (int r = 0; r < 4; ++r)
          Pl[(w * 32 + fm * 16 + quad * 4 + r) * 72 + nf * 16 + l16] = f2bf(s[fm][nf][r]);
#pragma unroll
    for (int fm = 0; fm < 2; ++fm)
#pragma unroll
      for (int f = 0; f < NFO; ++f)
#pragma unroll
        for (int r = 0; r < 4; ++r) O[fm][f][r] *= alpha[fm][r];
    bf16x8 pf[2][2];
#pragma unroll
    for (int fm = 0; fm < 2; ++fm)
#pragma unroll
      for (int kk2 = 0; kk2 < 2; ++kk2)
        pf[fm][kk2] = *(const bf16x8*)&Pl[(w * 32 + fm * 16 + l16) * 72 + kk2 * 32 + quad * 8];
#pragma unroll
    for (int f = 0; f < NFO; ++f)
#pragma unroll
      for (int kk2 = 0; kk2 < 2; ++kk2) {
        bf16x8 vf = *(const bf16x8*)&Vl[(f * 16 + l16) * 72 + kk2 * 32 + quad * 8];
        O[0][f] = __builtin_amdgcn_mfma_f32_16x16x32_bf16(pf[0][kk2], vf, O[0][f], 0, 0, 0);
        O[1][f] = __builtin_amdgcn_mfma_f32_16x16x32_bf16(pf[1][kk2], vf, O[1][f], 0, 0, 0);
      }
  }
  // ---- write partials ----
  const long t = ((long)z * gridDim.y + blockIdx.y) * gridDim.x + blockIdx.x;
  float* PO = p.partO + t * (128 * DH);
  float* PM = p.partML + t * 256;
#pragma unroll
  for (int fm = 0; fm < 2; ++fm) {
#pragma unroll
    for (int f = 0; f < NFO; ++f)
#pragma unroll
      for (int r = 0; r < 4; ++r)
        PO[(long)(w * 32 + fm * 16 + quad * 4 + r) * DH + f * 16 + l16] = O[fm][f][r];
    if (l16 == 0) {
#pragma unroll
      for (int r = 0; r < 4; ++r) {
        PM[(w * 32 + fm * 16 + quad * 4 + r) * 2 + 0] = m_[fm][r];
        PM[(w * 32 + fm * 16 + quad * 4 + r) * 2 + 1] = l_[fm][r];
      }
    }
  }
}

// ---------------- flash pass 2: merge NS segment partials, normalize, store bf16 ----------
struct MergeP {
  const float* partO; const float* partML; bf16_t* C;
  long ldc, sCb;
  int nh, y;
};

template <int DH, int NS>
__global__ __launch_bounds__(256) void fmerge_kernel(MergeP p) {
  const int tid = threadIdx.x;
  const int r = tid >> 1, ch = tid & 1;          // 128 rows x 2 col-halves
  const int blk = blockIdx.x;
  const int z = blk / p.y, qb = blk % p.y;
  const int zb = z / p.nh, zh = z % p.nh;
  const long t0 = (long)blk * NS;
  float mm[NS], wgt[NS];
  float mstar = -1e30f;
#pragma unroll
  for (int s = 0; s < NS; ++s) {
    mm[s] = p.partML[(t0 + s) * 256 + r * 2];
    mstar = fmaxf(mstar, mm[s]);
  }
  float lsum = 0.f;
#pragma unroll
  for (int s = 0; s < NS; ++s) {
    wgt[s] = __expf(mm[s] - mstar);
    lsum += wgt[s] * p.partML[(t0 + s) * 256 + r * 2 + 1];
  }
  const float inv = 1.0f / lsum;
  const int c0 = ch * (DH / 2);
  bf16_t* Cp = p.C + (long)zb * p.sCb + (long)(qb * 128 + r) * p.ldc + (long)zh * DH + c0;
#pragma unroll
  for (int c = 0; c < DH / 2; c += 4) {
    float4 acc = make_float4(0.f, 0.f, 0.f, 0.f);
#pragma unroll
    for (int s = 0; s < NS; ++s) {
      float4 v = *(const float4*)(p.partO + (t0 + s) * (128 * DH) + (long)r * DH + c0 + c);
      acc.x += wgt[s] * v.x; acc.y += wgt[s] * v.y;
      acc.z += wgt[s] * v.z; acc.w += wgt[s] * v.w;
    }
    ushort4 o;
    o.x = f2bf(acc.x * inv); o.y = f2bf(acc.y * inv);
    o.z = f2bf(acc.z * inv); o.w = f2bf(acc.w * inv);
    *(ushort4*)(Cp + c) = o;
  }
}

// ---------------- host ----------------
#define MB(x) ((long)(x) << 20)

extern "C" void kernel_launch(void* const* d_in, const int* in_sizes, int n_in,
                              void* d_out, int out_size, void* d_ws, size_t ws_size,
                              hipStream_t stream) {
  const float* motion      = (const float*)d_in[0];
  const float* scene_feats = (const float*)d_in[2];
  const float* prior       = (const float*)d_in[3];
  const float* ln1_g = (const float*)d_in[4];
  const float* ln1_b = (const float*)d_in[5];
  const float* qkv_w = (const float*)d_in[6];
  const float* qkv_b = (const float*)d_in[7];
  const float* out_w = (const float*)d_in[8];
  const float* out_b = (const float*)d_in[9];
  const float* ln2_g = (const float*)d_in[10];
  const float* ln2_b = (const float*)d_in[11];
  const float* ff1_w = (const float*)d_in[12];
  const float* ff1_b = (const float*)d_in[13];
  const float* ff2_w = (const float*)d_in[14];
  const float* ff2_b = (const float*)d_in[15];
  const float* saq_w = (const float*)d_in[16];
  const float* saq_b = (const float*)d_in[17];
  const float* sakv_w = (const float*)d_in[18];
  const float* sakv_b = (const float*)d_in[19];
  const float* saout_w = (const float*)d_in[20];
  const float* saout_b = (const float*)d_in[21];
  const float* fc1_w = (const float*)d_in[22];
  const float* fc1_b = (const float*)d_in[23];
  const float* fc2_w = (const float*)d_in[24];
  const float* fc2_b = (const float*)d_in[25];

  char* W = (char*)d_ws;
  bf16_t* h_bf    = (bf16_t*)(W + MB(0));    // 4 MB
  float*  x_f     = (float*) (W + MB(4));    // 8 MB
  bf16_t* o_ff    = (bf16_t*)(W + MB(12));   // 4 MB  enc-attn out, then ff1g
  bf16_t* qkv_bf  = (bf16_t*)(W + MB(16));   // 12 MB
  bf16_t* qsa     = (bf16_t*)(W + MB(28));   // 4 MB
  bf16_t* sm_bf   = (bf16_t*)(W + MB(32));   // 4 MB
  bf16_t* cat_bf  = (bf16_t*)(W + MB(36));   // 8 MB  [msca | smf]; pre-enc: enc partML
  bf16_t* fc1g    = (bf16_t*)(W + MB(44));   // 16 MB; pre-fc1: enc partO
  bf16_t* vTe     = (bf16_t*)(W + MB(60));   // 4 MB  enc V^T; post-enc: SA partML
  bf16_t* kv_bf   = (bf16_t*)(W + MB(64));   // 64 MB [32768][1024]
  bf16_t* vT      = (bf16_t*)(W + MB(128));  // 32 MB SA V^T  [32 z][128][4096]
  bf16_t* wbase   = (bf16_t*)(W + MB(160));  // 11.5 MB bf16 weights
  bf16_t* scene_bf= (bf16_t*)(W + MB(172));  // 32 MB; post-kv: SA partO (32 MB)

  float* encO  = (float*)fc1g;               // 16 MB (64z*4y*2s tiles x 128x64 f32)
  float* encML = (float*)cat_bf;             // 0.5 MB
  float* saO   = (float*)scene_bf;           // 32 MB (32z*4y*4s tiles x 128x128 f32)
  float* saML  = (float*)vTe;                // 0.5 MB

  bf16_t* wq   = wbase + 0L;
  bf16_t* wout = wbase + 786432L;
  bf16_t* wff1 = wbase + 1048576L;
  bf16_t* wff2 = wbase + 1310720L;
  bf16_t* wsaq = wbase + 1572864L;
  bf16_t* wskv = wbase + 1835008L;
  bf16_t* wsout= wbase + 2359296L;
  bf16_t* wfc1 = wbase + 2621440L;
  bf16_t* wfc2 = wbase + 4718592L;

  const dim3 B256(256);
  auto cvt = [&](const float* s, bf16_t* d, long n) {
    int n4 = (int)(n / 4);
    f2bf_kernel<<<(n4 + 255) / 256, B256, 0, stream>>>((const float4*)s, (ushort4*)d, n4);
  };
  cvt(qkv_w,  wq,   786432);
  cvt(out_w,  wout, 262144);
  cvt(ff1_w,  wff1, 262144);
  cvt(ff2_w,  wff2, 262144);
  cvt(saq_w,  wsaq, 262144);
  cvt(sakv_w, wskv, 524288);
  cvt(saout_w,wsout,262144);
  cvt(fc1_w,  wfc1, 2097152);
  cvt(fc2_w,  wfc2, 1048576);
  cvt(scene_feats, scene_bf, 16777216);

  // 1. h = LN1(motion)
  ln_kernel<<<1024, B256, 0, stream>>>(motion, ln1_g, ln1_b, h_bf);

  // 2. qkv = h @ qkv_w^T + b  [4096,1536]
  { MmaNT p{}; p.scale=1.f; p.zdiv=1; p.cBf=1;
    p.A=h_bf; p.lda=512; p.W=wq; p.ldw=512; p.bias=qkv_b;
    p.C=qkv_bf; p.ldc=1536; p.K=512;
    mma_nt_kernel<128><<<dim3(12,32,1), B256, 0, stream>>>(p); }

  // 3. encoder attention: V^T -> split flash (NS=2) -> merge
  { TransP t{}; t.src=qkv_bf+1024; t.dst=vTe; t.sSb=786432; t.sSh=64;
    t.ld=1536; t.nh=8; t.N=512; t.D=64;
    transpose_kernel<<<dim3(8,1,64), B256, 0, stream>>>(t); }
  { FlashP2 p{};
    p.Q=qkv_bf;     p.ldq=1536; p.sQb=786432; p.sQh=64;
    p.K=qkv_bf+512; p.ldk=1536; p.sKb=786432; p.sKh=64;
    p.VT=vTe; p.sVz=32768;
    p.prior=nullptr; p.sPb=0;
    p.partO=encO; p.partML=encML;
    p.nh=8; p.N=512; p.segN=256; p.scale=0.125f;
    flash3_kernel<64,0><<<dim3(2,4,64), B256, 0, stream>>>(p); }
  { MergeP m{}; m.partO=encO; m.partML=encML; m.C=o_ff;
    m.ldc=512; m.sCb=262144; m.nh=8; m.y=4;
    fmerge_kernel<64,2><<<256, B256, 0, stream>>>(m); }

  // 4. x = motion + o @ out_w^T + b   (fp32)
  { MmaNT p{}; p.scale=1.f; p.zdiv=1;
    p.A=o_ff; p.lda=512; p.W=wout; p.ldw=512; p.bias=out_b;
    p.res=motion; p.ldr=512;
    p.C=x_f; p.ldc=512; p.K=512;
    mma_nt_kernel<64><<<dim3(4,64,1), B256, 0, stream>>>(p); }

  // 5. h2 = LN2(x)
  ln_kernel<<<1024, B256, 0, stream>>>(x_f, ln2_g, ln2_b, h_bf);

  // 6. ff1g = gelu(h2 @ ff1_w^T + b)
  { MmaNT p{}; p.scale=1.f; p.zdiv=1; p.cBf=1; p.act=1;
    p.A=h_bf; p.lda=512; p.W=wff1; p.ldw=512; p.bias=ff1_b;
    p.C=o_ff; p.ldc=512; p.K=512;
    mma_nt_kernel<64><<<dim3(4,64,1), B256, 0, stream>>>(p); }

  // 7. msca = x + ff1g @ ff2_w^T + b  -> cat[:, 0:512]
  { MmaNT p{}; p.scale=1.f; p.zdiv=1; p.cBf=1;
    p.A=o_ff; p.lda=512; p.W=wff2; p.ldw=512; p.bias=ff2_b;
    p.res=x_f; p.ldr=512;
    p.C=cat_bf; p.ldc=1024; p.K=512;
    mma_nt_kernel<64><<<dim3(4,64,1), B256, 0, stream>>>(p); }

  // 8. q_sa = (msca @ saq_w^T + b) * 512^-0.5
  { MmaNT p{}; p.zdiv=1; p.cBf=1; p.scale=0.04419417382415922f;
    p.A=cat_bf; p.lda=1024; p.W=wsaq; p.ldw=512; p.bias=saq_b;
    p.C=qsa; p.ldc=512; p.K=512;
    mma_nt_kernel<64><<<dim3(4,64,1), B256, 0, stream>>>(p); }

  // 9. kv = scene @ sakv_w^T + b   [32768,1024]
  { MmaNT p{}; p.scale=1.f; p.zdiv=1; p.cBf=1;
    p.A=scene_bf; p.lda=512; p.W=wskv; p.ldw=512; p.bias=sakv_b;
    p.C=kv_bf; p.ldc=1024; p.K=512;
    mma_nt_kernel<128><<<dim3(8,256,1), B256, 0, stream>>>(p); }

  // 10. SA attention: V^T -> split flash (NS=4, prior prefetched) -> merge
  { TransP t{}; t.src=kv_bf+512; t.dst=vT; t.sSb=4194304; t.sSh=128;
    t.ld=1024; t.nh=4; t.N=4096; t.D=128;
    transpose_kernel<<<dim3(64,2,32), B256, 0, stream>>>(t); }
  { FlashP2 p{};
    p.Q=qsa;   p.ldq=128;  p.sQb=262144;  p.sQh=65536;
    p.K=kv_bf; p.ldk=1024; p.sKb=4194304; p.sKh=128;
    p.VT=vT; p.sVz=524288;
    p.prior=prior; p.sPb=2097152;
    p.partO=saO; p.partML=saML;
    p.nh=4; p.N=4096; p.segN=1024; p.scale=1.f;
    flash3_kernel<128,1><<<dim3(4,4,32), B256, 0, stream>>>(p); }
  { MergeP m{}; m.partO=saO; m.partML=saML; m.C=sm_bf;
    m.ldc=512; m.sCb=262144; m.nh=4; m.y=4;
    fmerge_kernel<128,4><<<128, B256, 0, stream>>>(m); }

  // 11. smf = sm @ saout_w^T + b  -> cat[:, 512:1024]
  { MmaNT p{}; p.scale=1.f; p.zdiv=1; p.cBf=1;
    p.A=sm_bf; p.lda=512; p.W=wsout; p.ldw=512; p.bias=saout_b;
    p.C=cat_bf + 512; p.ldc=1024; p.K=512;
    mma_nt_kernel<64><<<dim3(4,64,1), B256, 0, stream>>>(p); }

  // 12. fc1g = gelu(cat @ fc1_w^T + b)   [4096,2048]
  { MmaNT p{}; p.scale=1.f; p.zdiv=1; p.cBf=1; p.act=1;
    p.A=cat_bf; p.lda=1024; p.W=wfc1; p.ldw=1024; p.bias=fc1_b;
    p.C=fc1g; p.ldc=2048; p.K=1024;
    mma_nt_kernel<128><<<dim3(16,32,1), B256, 0, stream>>>(p); }

  // 13. out = fc1g @ fc2_w^T + b  -> d_out fp32
  { MmaNT p{}; p.scale=1.f; p.zdiv=1;
    p.A=fc1g; p.lda=2048; p.W=wfc2; p.ldw=2048; p.bias=fc2_b;
    p.C=d_out; p.ldc=512; p.K=2048;
    mma_nt_kernel<64><<<dim3(4,64,1), B256, 0, stream>>>(p); }
}